// Round 17
// baseline (210.283 us; speedup 1.0000x reference)
//
#include <hip/hip_runtime.h>
#include <hip/hip_bf16.h>
#include <hip/hip_cooperative_groups.h>

namespace cg = cooperative_groups;

// ContextModule R17: stage-1 rowsum+colsum fused into ONE cooperative kernel
// (scores computed once, kept in registers across grid.sync()); qkc grid
// flattened to 672 useful blocks. 8 dispatches, ws 55.6 MB.

typedef short bhalf8 __attribute__((ext_vector_type(8)));   // 8 bf16 = 4 VGPR
typedef float f32x4 __attribute__((ext_vector_type(4)));

#define SCALE 0.08838834764831845f  // 1/sqrt(128)

// ---- ws layout (float offsets) ----
#define OFF_QBF    ((size_t)0)               // qbf bf16 [8192][512]
#define OFF_RB     ((size_t)6193152)         // encbf -> kcbf -> obf bf16 [8192][512]
#define OFF_TMP    ((size_t)8290304)
#define OFF_PART   (OFF_TMP)                 // [256][2000] f32 colsum partials
#define OFF_CS     (OFF_TMP + 1024000)       // cs [2048] f32
#define OFF_IDX    (OFF_TMP + 1026048)       // 128 ints
#define OFF_RSP    (OFF_TMP + 1026176)       // rowsum partials [4096][8] f32
#define OFF_CEBF   ((size_t)12484608)        // ce bf16 [2000][512]
#define OFF_K2BF   ((size_t)13022608)        // k2 bf16 [101][512]
#define OFF_V2TP   ((size_t)13074608)        // v2tp bf16 [4][128][128]
#define OFF_WQBF   ((size_t)13107376)
#define OFF_WKBF   ((size_t)13238448)
#define OFF_WVBF   ((size_t)13369520)
#define OFF_WCBF   ((size_t)13500592)
#define OFF_WOTBF  ((size_t)13631664)
#define OFF_WC2BF  ((size_t)13762736)
#define OFF_BC2    ((size_t)13893808)        // 512
// total 13,894,320 fl = 55.6 MB

__device__ __forceinline__ float bf2f(short u) {
    union { float f; unsigned int i; } x;
    x.i = ((unsigned int)(unsigned short)u) << 16;
    return x.f;
}
__device__ __forceinline__ ushort f2b(float f) {
    union { float f; unsigned int i; } x; x.f = f;
    return (ushort)((x.i + 0x7fff + ((x.i >> 16) & 1)) >> 16);  // RNE
}

// async global->LDS, 16B per lane; LDS dest = wave-uniform base + lane*16
__device__ __forceinline__ void gld16(ushort* lds, const ushort* g) {
    __builtin_amdgcn_global_load_lds(
        (const __attribute__((address_space(1))) unsigned int*)g,
        (__attribute__((address_space(3))) unsigned int*)lds, 16, 0, 0);
}

// ---------------------------------------------------------------------------
// prep: f32->bf16 conversions + v2tp zero + bc2 + wo-transpose, one launch.
// ---------------------------------------------------------------------------
__global__ __launch_bounds__(256) void prep_kernel(
    const float* __restrict__ enc, const float* __restrict__ ce,
    const float* __restrict__ wq, const float* __restrict__ wk,
    const float* __restrict__ wv, const float* __restrict__ wc,
    const float* __restrict__ wo, const float* __restrict__ bo,
    const float* __restrict__ bcb,
    ushort* __restrict__ encbf, ushort* __restrict__ cebf,
    ushort* __restrict__ wqbf, ushort* __restrict__ wkbf,
    ushort* __restrict__ wvbf, ushort* __restrict__ wcbf,
    ushort* __restrict__ v2tp, ushort* __restrict__ wotbf,
    float* __restrict__ bc2)
{
    __shared__ float tile[32][33];
    const int b = blockIdx.x, tid = threadIdx.x;
    const float* s; ushort* d; int n4, base;
    if (b < 4096)      { s = enc; d = encbf; n4 = 1048576; base = b; }
    else if (b < 5096) { s = ce;  d = cebf;  n4 = 256000;  base = b - 4096; }
    else if (b < 5352) { s = wq;  d = wqbf;  n4 = 65536;   base = b - 5096; }
    else if (b < 5608) { s = wk;  d = wkbf;  n4 = 65536;   base = b - 5352; }
    else if (b < 5864) { s = wv;  d = wvbf;  n4 = 65536;   base = b - 5608; }
    else if (b < 6120) { s = wc;  d = wcbf;  n4 = 65536;   base = b - 5864; }
    else if (b < 6152) {
        const int i = (b - 6120) * 256 + tid;          // 8192 uint4
        ((uint4*)v2tp)[i] = make_uint4(0u, 0u, 0u, 0u);
        return;
    } else if (b < 6154) {
        const int dd = (b - 6152) * 256 + tid;
        float acc = bcb[dd];
        const float4* wr = (const float4*)(wc + (size_t)dd * 512);
        const float4* br = (const float4*)bo;
        for (int m4 = 0; m4 < 128; ++m4) {
            const float4 w4 = wr[m4], b4 = br[m4];
            acc += w4.x * b4.x + w4.y * b4.y + w4.z * b4.z + w4.w * b4.w;
        }
        bc2[dd] = acc;
        return;
    } else {
        const int b2 = b - 6154;                       // 256 tiles
        const int bx = (b2 & 15) * 32, by = (b2 >> 4) * 32;
        const int tx = tid & 31, ty = tid >> 5;        // 32x8
        #pragma unroll
        for (int rr = 0; rr < 4; ++rr)
            tile[ty + 8 * rr][tx] = wo[(size_t)(by + ty + 8 * rr) * 512 + bx + tx];
        __syncthreads();
        #pragma unroll
        for (int rr = 0; rr < 4; ++rr)
            wotbf[(size_t)(bx + ty + 8 * rr) * 512 + by + tx] =
                f2b(tile[tx][ty + 8 * rr]);
        return;
    }
    const int i = base * 256 + tid;
    if (i >= n4) return;
    const float4 v = ((const float4*)s)[i];
    ushort4 r;
    r.x = f2b(v.x); r.y = f2b(v.y); r.z = f2b(v.z); r.w = f2b(v.w);
    ((ushort4*)d)[i] = r;
}

// ---------------------------------------------------------------------------
// 64x128 MFMA GEMM body, BK=64, double-buffered, one barrier per K-step.
// ---------------------------------------------------------------------------
__device__ __forceinline__ void stage_ab(
    const ushort* gA, const ushort* gB0, const ushort* gB1, int k0,
    ushort* As, ushort* Bs, int wave)
{
    gld16(As + wave * 512,        gA  + k0);
    gld16(As + 2048 + wave * 512, gA  + k0 + 32);
    gld16(Bs + wave * 512,        gB0 + k0);
    gld16(Bs + 4096 + wave * 512, gB0 + k0 + 32);
    gld16(Bs + 2048 + wave * 512, gB1 + k0);
    gld16(Bs + 6144 + wave * 512, gB1 + k0 + 32);
}

__device__ __forceinline__ void gemm_body_512(
    const ushort* A, const ushort* W, const float* bias, ushort* Cbf,
    int M, int bm, int bn, ushort* As, ushort* Bs, int rowA)
{
    const int tid = threadIdx.x;
    const int wave = tid >> 6, lane = tid & 63;
    const int wm = wave >> 1, wn = wave & 1;
    const int mr = lane & 15, g = lane >> 4;

    f32x4 acc[2][4];
    #pragma unroll
    for (int i = 0; i < 2; ++i)
        #pragma unroll
        for (int j = 0; j < 4; ++j)
            #pragma unroll
            for (int p = 0; p < 4; ++p) acc[i][j][p] = 0.f;

    const int r0 = tid >> 2, c0 = tid & 3;
    const int cA = (c0 ^ (r0 & 3)) * 8;
    const ushort* gA  = A + (size_t)rowA * 512 + cA;
    const ushort* gB0 = W + (size_t)(bn + r0) * 512 + cA;
    const ushort* gB1 = W + (size_t)(bn + r0 + 64) * 512 + cA;

    stage_ab(gA, gB0, gB1, 0, As, Bs, wave);
    for (int k0 = 0; k0 < 512; k0 += 64) {
        const int cur = (k0 >> 6) & 1;
        ushort* Ac = As + cur * 4096;
        ushort* Bc = Bs + cur * 8192;
        __syncthreads();   // drains cur's loads; other buf free
        if (k0 + 64 < 512)
            stage_ab(gA, gB0, gB1, k0 + 64,
                     As + (cur ^ 1) * 4096, Bs + (cur ^ 1) * 8192, wave);
        const int ksw = (g ^ (mr & 3)) << 3;
        #pragma unroll
        for (int h = 0; h < 2; ++h) {
            bhalf8 a[2], b[4];
            #pragma unroll
            for (int i = 0; i < 2; ++i)
                a[i] = *(const bhalf8*)
                    &Ac[h * 2048 + (wm * 32 + i * 16 + mr) * 32 + ksw];
            #pragma unroll
            for (int j = 0; j < 4; ++j)
                b[j] = *(const bhalf8*)
                    &Bc[h * 4096 + (wn * 64 + j * 16 + mr) * 32 + ksw];
            #pragma unroll
            for (int i = 0; i < 2; ++i)
                #pragma unroll
                for (int j = 0; j < 4; ++j)
                    acc[i][j] = __builtin_amdgcn_mfma_f32_16x16x32_bf16(
                        a[i], b[j], acc[i][j], 0, 0, 0);
        }
    }

    #pragma unroll
    for (int i = 0; i < 2; ++i) {
        #pragma unroll
        for (int j = 0; j < 4; ++j) {
            const int gn = bn + wn * 64 + j * 16 + mr;
            const float bb = bias ? bias[gn] : 0.f;
            #pragma unroll
            for (int p = 0; p < 4; ++p) {
                const int gm = bm + wm * 32 + i * 16 + g * 4 + p;
                if (gm >= M) continue;
                Cbf[(size_t)gm * 512 + gn] = f2b(acc[i][j][p] + bb);
            }
        }
    }
}

// q-proj / kc-proj / Wc2 in one FLAT launch: 672 blocks, no empty blocks.
// [0,512): z0 q-proj; [512,640): z1 kc; [640,672): z2 Wc2.
__global__ __launch_bounds__(256) void qkc_gemm(
    const ushort* __restrict__ encbf, const ushort* __restrict__ cebf,
    const ushort* __restrict__ wcbf,
    const ushort* __restrict__ wqbf, const ushort* __restrict__ wkbf,
    const ushort* __restrict__ wotbf,
    const float* __restrict__ bq, const float* __restrict__ bk,
    ushort* __restrict__ qbf, ushort* __restrict__ kcbf,
    ushort* __restrict__ wc2bf)
{
    __shared__ __align__(16) ushort As[2 * 64 * 64];
    __shared__ __align__(16) ushort Bs[2 * 128 * 64];
    const int bid = blockIdx.x;
    int z, x, y;
    if (bid < 512)      { z = 0; x = bid & 3; y = bid >> 2; }
    else if (bid < 640) { z = 1; x = (bid - 512) & 3; y = (bid - 512) >> 2; }
    else                { z = 2; x = (bid - 640) & 3; y = (bid - 640) >> 2; }
    const ushort* A = (z == 0) ? encbf : (z == 1) ? cebf : wcbf;
    const ushort* W = (z == 0) ? wqbf : (z == 1) ? wkbf : wotbf;
    const float* bias = (z == 0) ? bq : (z == 1) ? bk : nullptr;
    ushort* C = (z == 0) ? qbf : (z == 1) ? kcbf : wc2bf;
    const int M = (z == 0) ? 8192 : (z == 1) ? 2000 : 512;
    const int bm = y * 64;
    const int rowA = min(bm + (threadIdx.x >> 2), M - 1);
    gemm_body_512(A, W, bias, C, M, bm, x * 128, As, Bs, rowA);
}

// ---------------------------------------------------------------------------
// FUSED stage-1 (cooperative): scores computed ONCE, kept in registers
// across grid.sync(). grid (16 m, 4 h, 8 nc) = 512 blocks, 64KB LDS
// -> exactly 2 blocks/CU co-resident. Phase 1: rowsum partials -> rsp.
// grid.sync(). Phase 2: inv from rsp, colsum partials -> part.
// ---------------------------------------------------------------------------
__device__ __forceinline__ void stage_ktile(
    ushort* Ks, const ushort* kcbf, int nt, int h, int w, int lane)
{
    #pragma unroll
    for (int it = 0; it < 8; ++it) {
        const int u = it * 256 + (w << 6) + lane;   // 0..2047
        const int nl = u >> 4, c = u & 15;
        gld16(Ks + (size_t)(it * 256 + (w << 6)) * 8,
              kcbf + (size_t)(nt * 128 + nl) * 512 + (h << 7)
                   + ((c ^ (nl & 7)) << 3));
    }
}

__device__ __forceinline__ void score_tile(
    const ushort* Ks, const bhalf8* aq, int mr, int g, f32x4* sacc)
{
    #pragma unroll
    for (int jn = 0; jn < 8; ++jn)
        #pragma unroll
        for (int p = 0; p < 4; ++p) sacc[jn][p] = 0.f;
    #pragma unroll
    for (int kd = 0; kd < 4; ++kd) {
        #pragma unroll
        for (int jn = 0; jn < 8; ++jn) {
            const int n = (jn << 4) + mr;
            const bhalf8 bk = *(const bhalf8*)
                &Ks[(n << 7) + ((((kd << 2) + g) ^ (n & 7)) << 3)];
            sacc[jn] = __builtin_amdgcn_mfma_f32_16x16x32_bf16(
                aq[kd], bk, sacc[jn], 0, 0, 0);
        }
    }
}

__global__ __launch_bounds__(256) void stage1_fused(
    const ushort* __restrict__ qb, const ushort* __restrict__ kcbf,
    float* __restrict__ rsp, float* __restrict__ part)
{
    __shared__ __align__(16) ushort Ks[2 * 128 * 128];
    const int tid = threadIdx.x, w = tid >> 6, lane = tid & 63;
    const int mr = lane & 15, g = lane >> 4;
    const int h = blockIdx.y, nc = blockIdx.z;
    const int bm = blockIdx.x * 64;
    const int slot = ((h * 16 + blockIdx.x) << 2) + w;

    const ushort* qrow = qb + (size_t)(bm + (w << 4) + mr) * 512 + (h << 7);
    bhalf8 aq[4];
    #pragma unroll
    for (int kd = 0; kd < 4; ++kd)
        aq[kd] = *(const bhalf8*)(qrow + (g << 3) + (kd << 5));

    const int nt0 = nc * 2, nt1 = nc * 2 + 1;
    stage_ktile(Ks, kcbf, nt0, h, w, lane);
    __syncthreads();                                 // tile0 ready
    stage_ktile(Ks + 16384, kcbf, nt1, h, w, lane);  // tile1 in flight

    float rsl[4] = {0.f, 0.f, 0.f, 0.f};
    f32x4 e0[8], e1[8];
    score_tile(Ks, aq, mr, g, e0);
    #pragma unroll
    for (int jn = 0; jn < 8; ++jn) {
        const bool valid = nt0 * 128 + (jn << 4) + mr < 2000;
        #pragma unroll
        for (int p = 0; p < 4; ++p) {
            const float ev = valid ? __expf(e0[jn][p] * SCALE) : 0.f;
            e0[jn][p] = ev;
            rsl[p] += ev;
        }
    }
    __syncthreads();                                 // tile1 ready
    score_tile(Ks + 16384, aq, mr, g, e1);
    #pragma unroll
    for (int jn = 0; jn < 8; ++jn) {
        const bool valid = nt1 * 128 + (jn << 4) + mr < 2000;
        #pragma unroll
        for (int p = 0; p < 4; ++p) {
            const float ev = valid ? __expf(e1[jn][p] * SCALE) : 0.f;
            e1[jn][p] = ev;
            rsl[p] += ev;
        }
    }

    #pragma unroll
    for (int off = 1; off <= 8; off <<= 1)
        #pragma unroll
        for (int p = 0; p < 4; ++p)
            rsl[p] += __shfl_xor(rsl[p], off);
    if (mr == 0) {
        #pragma unroll
        for (int p = 0; p < 4; ++p) {
            const int row = (h << 10) + bm + (w << 4) + (g << 2) + p;
            rsp[(size_t)row * 8 + nc] = rsl[p];
        }
    }

    cg::this_grid().sync();   // all rsp partials visible

    float inv[4];
    #pragma unroll
    for (int p = 0; p < 4; ++p) {
        const int row = (h << 10) + bm + (w << 4) + (g << 2) + p;
        const float4 ra = *(const float4*)(rsp + (size_t)row * 8);
        const float4 rb = *(const float4*)(rsp + (size_t)row * 8 + 4);
        inv[p] = 1.f / (ra.x + ra.y + ra.z + ra.w + rb.x + rb.y + rb.z + rb.w);
    }

    #pragma unroll
    for (int t = 0; t < 2; ++t) {
        const int nt = t ? nt1 : nt0;
        #pragma unroll
        for (int jn = 0; jn < 8; ++jn) {
            const int n = nt * 128 + (jn << 4) + mr;
            const bool valid = n < 2000;
            float cv = 0.f;
            #pragma unroll
            for (int p = 0; p < 4; ++p)
                cv += (t ? e1[jn][p] : e0[jn][p]) * inv[p];  // invalid e == 0
            cv += __shfl_xor(cv, 16);
            cv += __shfl_xor(cv, 32);   // sum over the wave's 16 rows
            if (g == 0 && valid) part[(size_t)slot * 2000 + n] = cv;
        }
    }
}

// FULL reduction part[256][2000] -> cs[2000]; grid (8), 256 thr.
__global__ __launch_bounds__(256) void reduce_full_kernel(
    const float* __restrict__ part, float* __restrict__ cs)
{
    const int n = blockIdx.x * 256 + threadIdx.x;
    if (n >= 2000) return;
    float s = 0.f;
    for (int sl = 0; sl < 256; ++sl) s += part[(size_t)sl * 2000 + n];
    cs[n] = s;
}

// ---------------------------------------------------------------------------
// Top-101 of 2000 via MSB-first radix-select (ballot/popcount).
// ---------------------------------------------------------------------------
__global__ void topk_kernel(const float* __restrict__ cs,
                            int* __restrict__ idx)
{
    const int lane = threadIdx.x;   // block = 64
    const unsigned long long below = (1ull << lane) - 1ull;

    unsigned key[32];
    #pragma unroll
    for (int i = 0; i < 32; ++i) {
        const int n = lane + 64 * i;
        const float s = (n < 2000) ? cs[n] : -1e30f;
        const unsigned u = __float_as_uint(s);
        key[i] = u ^ ((unsigned)((int)u >> 31) | 0x80000000u);
    }

    unsigned prefix = 0;
    int remaining = 101;
    for (int b = 31; b >= 0; --b) {
        const unsigned tgt = (prefix << 1) | 1u;
        int cnt = 0;
        #pragma unroll
        for (int i = 0; i < 32; ++i)
            cnt += (int)__popcll(__ballot((key[i] >> b) == tgt));
        if (cnt >= remaining) prefix = tgt;
        else { remaining -= cnt; prefix = prefix << 1; }
    }
    const unsigned T = prefix;

    int base = 0;
    #pragma unroll
    for (int i = 0; i < 32; ++i) {
        const unsigned long long m = __ballot(key[i] > T);
        if (key[i] > T) idx[base + (int)__popcll(m & below)] = lane + 64 * i;
        base += (int)__popcll(m);
    }
    int r = remaining;
    #pragma unroll
    for (int i = 0; i < 32; ++i) {
        const unsigned long long m = __ballot(key[i] == T);
        const int cb = (int)__popcll(m & below);
        if (key[i] == T && cb < r) idx[base + cb] = lane + 64 * i;
        const int take = min(r, (int)__popcll(m));
        base += take; r -= take;
    }
}

// ---------------------------------------------------------------------------
// Fused k2/v2 projections with inline gather, dbuf BK=64 (z=0 k2; z=1 v2tp).
// ---------------------------------------------------------------------------
__global__ __launch_bounds__(256) void kv2_proj(
    const ushort* __restrict__ cebf, const int* __restrict__ idxbuf,
    const ushort* __restrict__ wkbf, const ushort* __restrict__ wvbf,
    const float* __restrict__ bk, const float* __restrict__ bv,
    ushort* __restrict__ k2bf, ushort* __restrict__ v2tp)
{
    __shared__ __align__(16) ushort As[2 * 64 * 64];
    __shared__ __align__(16) ushort Bs[2 * 128 * 64];
    const int z = blockIdx.z;
    const ushort* W = z ? wvbf : wkbf;
    const float* bias = z ? bv : bk;
    const int tid = threadIdx.x;
    const int wave = tid >> 6, lane = tid & 63;
    const int wm = wave >> 1, wn = wave & 1;
    const int mr = lane & 15, g = lane >> 4;
    const int bm = blockIdx.y * 64, bn = blockIdx.x * 128;

    f32x4 acc[2][4];
    #pragma unroll
    for (int i = 0; i < 2; ++i)
        #pragma unroll
        for (int j = 0; j < 4; ++j)
            #pragma unroll
            for (int p = 0; p < 4; ++p) acc[i][j][p] = 0.f;

    const int r0 = tid >> 2, c0 = tid & 3;
    const int cA = (c0 ^ (r0 & 3)) * 8;
    const int rA  = min(bm + r0, 100);
    const int srcrow = idxbuf[rA];               // inline gather
    const ushort* gA  = cebf + (size_t)srcrow * 512 + cA;
    const ushort* gB0 = W + (size_t)(bn + r0) * 512 + cA;
    const ushort* gB1 = W + (size_t)(bn + r0 + 64) * 512 + cA;

    stage_ab(gA, gB0, gB1, 0, As, Bs, wave);
    for (int k0 = 0; k0 < 512; k0 += 64) {
        const int cur = (k0 >> 6) & 1;
        ushort* Ac = As + cur * 4096;
        ushort* Bc = Bs + cur * 8192;
        __syncthreads();
        if (k0 + 64 < 512)
            stage_ab(gA, gB0, gB1, k0 + 64,
                     As + (cur ^ 1) * 4096, Bs + (cur ^ 1) * 8192, wave);
        const int ksw = (g ^ (mr & 3)) << 3;
        #pragma unroll
        for (int h = 0; h < 2; ++h) {
            bhalf8 a[2], b[4];
            #pragma unroll
            for (int i = 0; i < 2; ++i)
                a[i] = *(const bhalf8*)
                    &Ac[h * 2048 + (wm * 32 + i * 16 + mr) * 32 + ksw];
            #pragma unroll
            for (int j = 0; j < 4; ++j)
                b[j] = *(const bhalf8*)
                    &Bc[h * 4096 + (wn * 64 + j * 16 + mr) * 32 + ksw];
            #pragma unroll
            for (int i = 0; i < 2; ++i)
                #pragma unroll
                for (int j = 0; j < 4; ++j)
                    acc[i][j] = __builtin_amdgcn_mfma_f32_16x16x32_bf16(
                        a[i], b[j], acc[i][j], 0, 0, 0);
        }
    }

    #pragma unroll
    for (int i = 0; i < 2; ++i) {
        #pragma unroll
        for (int j = 0; j < 4; ++j) {
            const int gn = bn + wn * 64 + j * 16 + mr;
            const float bb = bias[gn];
            #pragma unroll
            for (int p = 0; p < 4; ++p) {
                const int gm = bm + wm * 32 + i * 16 + g * 4 + p;
                if (gm >= 101) continue;
                const ushort v = f2b(acc[i][j][p] + bb);
                if (z == 0) k2bf[(size_t)gm * 512 + gn] = v;
                else        v2tp[(size_t)gn * 128 + gm] = v;
            }
        }
    }
}

// ---------------------------------------------------------------------------
// Fused stage-2 attention, 8 waves x 128 rows per block. grid (64, 4).
// ---------------------------------------------------------------------------
__global__ __launch_bounds__(512) void attn2_fused(
    const ushort* __restrict__ qb, const ushort* __restrict__ k2bf,
    const ushort* __restrict__ v2tp, ushort* __restrict__ obf)
{
    __shared__ __align__(16) ushort K2s[128 * 128];
    __shared__ __align__(16) ushort V2s[128 * 128];
    __shared__ __align__(16) ushort Ps[8 * 16 * 128];
    const int tid = threadIdx.x, w = tid >> 6, lane = tid & 63;
    const int mr = lane & 15, g = lane >> 4;
    const int h = blockIdx.y;
    const int bm = blockIdx.x * 128;

    #pragma unroll
    for (int it = 0; it < 4; ++it) {
        const int cl = tid + 512 * it;      // 0..2047
        const int n = cl >> 4, c = cl & 15;
        uint4 kv = make_uint4(0u, 0u, 0u, 0u);
        if (n < 101)
            kv = *(const uint4*)(k2bf + (size_t)n * 512 + h * 128 + c * 8);
        *(uint4*)&K2s[(n << 7) + ((c ^ (n & 7)) << 3)] = kv;
        const uint4 vv = *(const uint4*)(v2tp + (((size_t)h << 7) + n) * 128 + c * 8);
        *(uint4*)&V2s[(n << 7) + ((c ^ (n & 7)) << 3)] = vv;
    }
    __syncthreads();

    f32x4 sacc[8];
    #pragma unroll
    for (int jn = 0; jn < 8; ++jn)
        #pragma unroll
        for (int p = 0; p < 4; ++p) sacc[jn][p] = 0.f;
    const ushort* qrow = qb + (size_t)(bm + (w << 4) + mr) * 512 + (h << 7);
    #pragma unroll
    for (int kd = 0; kd < 4; ++kd) {
        const bhalf8 aq = *(const bhalf8*)(qrow + (g << 3) + (kd << 5));
        #pragma unroll
        for (int jn = 0; jn < 8; ++jn) {
            const int n = (jn << 4) + mr;
            const bhalf8 bk = *(const bhalf8*)
                &K2s[(n << 7) + ((((kd << 2) + g) ^ (n & 7)) << 3)];
            sacc[jn] = __builtin_amdgcn_mfma_f32_16x16x32_bf16(aq, bk, sacc[jn], 0, 0, 0);
        }
    }

    float mrow[4] = {-1e30f, -1e30f, -1e30f, -1e30f};
    #pragma unroll
    for (int jn = 0; jn < 8; ++jn) {
        const bool valid = (jn < 6) || (jn == 6 && mr < 5);
        #pragma unroll
        for (int p = 0; p < 4; ++p) {
            const float s = valid ? sacc[jn][p] * SCALE : -1e30f;
            sacc[jn][p] = s;
            mrow[p] = fmaxf(mrow[p], s);
        }
    }
    #pragma unroll
    for (int off = 1; off <= 8; off <<= 1)
        #pragma unroll
        for (int p = 0; p < 4; ++p)
            mrow[p] = fmaxf(mrow[p], __shfl_xor(mrow[p], off));
    float srow[4] = {0.f, 0.f, 0.f, 0.f};
    #pragma unroll
    for (int jn = 0; jn < 8; ++jn)
        #pragma unroll
        for (int p = 0; p < 4; ++p) {
            const float e = __expf(sacc[jn][p] - mrow[p]);
            sacc[jn][p] = e;
            srow[p] += e;
        }
    #pragma unroll
    for (int off = 1; off <= 8; off <<= 1)
        #pragma unroll
        for (int p = 0; p < 4; ++p)
            srow[p] += __shfl_xor(srow[p], off);
    float inv[4];
    #pragma unroll
    for (int p = 0; p < 4; ++p) inv[p] = 1.f / srow[p];

    ushort* pw = Ps + (w << 11);
    #pragma unroll
    for (int jn = 0; jn < 8; ++jn) {
        const int cb = (jn << 1) + (mr >> 3);
        #pragma unroll
        for (int p = 0; p < 4; ++p) {
            const int r = (g << 2) + p;
            pw[(r << 7) + ((cb ^ (r & 7)) << 3) + (mr & 7)] =
                f2b(sacc[jn][p] * inv[p]);
        }
    }

    f32x4 oacc[8];
    #pragma unroll
    for (int jd = 0; jd < 8; ++jd)
        #pragma unroll
        for (int p = 0; p < 4; ++p) oacc[jd][p] = 0.f;
    #pragma unroll
    for (int kn = 0; kn < 4; ++kn) {
        const int ck = (kn << 2) + g;
        const bhalf8 ap = *(const bhalf8*)
            &pw[(mr << 7) + ((ck ^ (mr & 7)) << 3)];
        #pragma unroll
        for (int jd = 0; jd < 8; ++jd) {
            const int d = (jd << 4) + mr;
            const bhalf8 bv = *(const bhalf8*)
                &V2s[(d << 7) + ((ck ^ (d & 7)) << 3)];
            oacc[jd] = __builtin_amdgcn_mfma_f32_16x16x32_bf16(ap, bv, oacc[jd], 0, 0, 0);
        }
    }

    #pragma unroll
    for (int jd = 0; jd < 8; ++jd)
        #pragma unroll
        for (int p = 0; p < 4; ++p) {
            const int row = bm + (w << 4) + (g << 2) + p;
            obf[(size_t)row * 512 + (h << 7) + (jd << 4) + mr] = f2b(oacc[jd][p]);
        }
}

// ---------------------------------------------------------------------------
// Fused final projection + residual + LayerNorm, dbuf BK=64.
// ---------------------------------------------------------------------------
__device__ __forceinline__ void pl_stage(
    const ushort* gA, const ushort* gB, int k0,
    ushort* Asb, ushort* Bsb, int w)
{
    if (w < 2) {
        gld16(Asb + w * 512,        gA + k0);
        gld16(Asb + 1024 + w * 512, gA + k0 + 32);
    }
    #pragma unroll
    for (int r = 0; r < 8; ++r) {
        const int nb = r * 4 + w;              // 0..31 groups of 16 rows
        gld16(Bsb + nb * 512,         gB + nb * 8192 + k0);
        gld16(Bsb + 16384 + nb * 512, gB + nb * 8192 + k0 + 32);
    }
}

__global__ __launch_bounds__(256) void proj_ln(
    const ushort* __restrict__ obf, const ushort* __restrict__ wc2bf,
    const float* __restrict__ bc2, const float* __restrict__ enc,
    const float* __restrict__ gw, const float* __restrict__ bta,
    float* __restrict__ out)
{
    __shared__ __align__(16) ushort As[2 * 2048];
    __shared__ __align__(16) ushort Bs[2 * 32768];
    __shared__ float red1[2][32], red2[2][32];
    const int tid = threadIdx.x, w = tid >> 6, lane = tid & 63;
    const int mr = lane & 15, gq = lane >> 4;
    const int rh = w & 1, ch = w >> 1;
    const int bm = blockIdx.x * 32;

    f32x4 acc[16];
    #pragma unroll
    for (int j = 0; j < 16; ++j)
        #pragma unroll
        for (int p = 0; p < 4; ++p) acc[j][p] = 0.f;

    const int lr = lane >> 2, lc = lane & 3;
    const int swc = (lc ^ (lr & 3)) * 8;
    const ushort* gA = obf + (size_t)(bm + ((w & 1) << 4) + lr) * 512 + swc;
    const ushort* gB = wc2bf + (size_t)lr * 512 + swc;

    pl_stage(gA, gB, 0, As, Bs, w);
    for (int k0 = 0; k0 < 512; k0 += 64) {
        const int cur = (k0 >> 6) & 1;
        ushort* Ac = As + cur * 2048;
        ushort* Bc = Bs + cur * 32768;
        __syncthreads();
        if (k0 + 64 < 512)
            pl_stage(gA, gB, k0 + 64,
                     As + (cur ^ 1) * 2048, Bs + (cur ^ 1) * 32768, w);
        const int ksw = (gq ^ (mr & 3)) << 3;
        #pragma unroll
        for (int h = 0; h < 2; ++h) {
            const bhalf8 a = *(const bhalf8*)
                &Ac[h * 1024 + (((rh << 4) + mr) << 5) + ksw];
            #pragma unroll
            for (int j = 0; j < 16; ++j) {
                const int n = (ch << 8) + (j << 4) + mr;
                const bhalf8 b = *(const bhalf8*)
                    &Bc[h * 16384 + (n << 5) + ksw];
                acc[j] = __builtin_amdgcn_mfma_f32_16x16x32_bf16(a, b, acc[j], 0, 0, 0);
            }
        }
    }

    float s1[4] = {0.f, 0.f, 0.f, 0.f}, s2[4] = {0.f, 0.f, 0.f, 0.f};
    #pragma unroll
    for (int j = 0; j < 16; ++j) {
        const int gcol = (ch << 8) + (j << 4) + mr;
        const float bb = bc2[gcol];
        #pragma unroll
        for (int p = 0; p < 4; ++p) {
            const int grow = bm + (rh << 4) + (gq << 2) + p;
            const float x = acc[j][p] + bb + enc[(size_t)grow * 512 + gcol];
            acc[j][p] = x;
            s1[p] += x;
            s2[p] += x * x;
        }
    }
    #pragma unroll
    for (int off = 1; off <= 8; off <<= 1)
        #pragma unroll
        for (int p = 0; p < 4; ++p) {
            s1[p] += __shfl_xor(s1[p], off);
            s2[p] += __shfl_xor(s2[p], off);
        }
    if (mr == 0) {
        #pragma unroll
        for (int p = 0; p < 4; ++p) {
            red1[ch][(rh << 4) + (gq << 2) + p] = s1[p];
            red2[ch][(rh << 4) + (gq << 2) + p] = s2[p];
        }
    }
    __syncthreads();
    float mu[4], rstd[4];
    #pragma unroll
    for (int p = 0; p < 4; ++p) {
        const int ri = (rh << 4) + (gq << 2) + p;
        const float t1 = red1[0][ri] + red1[1][ri];
        const float t2 = red2[0][ri] + red2[1][ri];
        const float m = t1 * (1.f / 512.f);
        mu[p] = m;
        rstd[p] = rsqrtf(t2 * (1.f / 512.f) - m * m + 1e-5f);
    }
    #pragma unroll
    for (int j = 0; j < 16; ++j) {
        const int gcol = (ch << 8) + (j << 4) + mr;
        const float gg = gw[gcol], bb = bta[gcol];
        #pragma unroll
        for (int p = 0; p < 4; ++p) {
            const int grow = bm + (rh << 4) + (gq << 2) + p;
            out[(size_t)grow * 512 + gcol] = (acc[j][p] - mu[p]) * rstd[p] * gg + bb;
        }
    }
}

extern "C" void kernel_launch(void* const* d_in, const int* in_sizes, int n_in,
                              void* d_out, int out_size, void* d_ws, size_t ws_size,
                              hipStream_t stream)
{
    const float* ce  = (const float*)d_in[0];
    const float* enc = (const float*)d_in[1];
    const float* wq  = (const float*)d_in[2];
    const float* bq  = (const float*)d_in[3];
    const float* wk  = (const float*)d_in[4];
    const float* bk  = (const float*)d_in[5];
    const float* wv  = (const float*)d_in[6];
    const float* bv  = (const float*)d_in[7];
    const float* wo  = (const float*)d_in[8];
    const float* bo  = (const float*)d_in[9];
    const float* wc  = (const float*)d_in[10];
    const float* bcb = (const float*)d_in[11];
    const float* lng = (const float*)d_in[12];
    const float* lnb = (const float*)d_in[13];
    float* ws  = (float*)d_ws;
    float* out = (float*)d_out;

    ushort* qbf    = (ushort*)(ws + OFF_QBF);
    ushort* encbf  = (ushort*)(ws + OFF_RB);     // -> kcbf -> obf
    ushort* kcbf   = (ushort*)(ws + OFF_RB);
    ushort* obf    = (ushort*)(ws + OFF_RB);
    float*  part   = ws + OFF_PART;
    float*  cs     = ws + OFF_CS;
    int*    idx    = (int*)(ws + OFF_IDX);
    float*  rsp    = ws + OFF_RSP;
    ushort* cebf   = (ushort*)(ws + OFF_CEBF);
    ushort* k2bf   = (ushort*)(ws + OFF_K2BF);
    ushort* v2tp   = (ushort*)(ws + OFF_V2TP);
    ushort* wqbf   = (ushort*)(ws + OFF_WQBF);
    ushort* wkbf   = (ushort*)(ws + OFF_WKBF);
    ushort* wvbf   = (ushort*)(ws + OFF_WVBF);
    ushort* wcbf   = (ushort*)(ws + OFF_WCBF);
    ushort* wotbf  = (ushort*)(ws + OFF_WOTBF);
    ushort* wc2bf  = (ushort*)(ws + OFF_WC2BF);
    float*  bc2    = ws + OFF_BC2;

    prep_kernel<<<6410, 256, 0, stream>>>(enc, ce, wq, wk, wv, wc, wo, bo, bcb,
                                          encbf, cebf, wqbf, wkbf, wvbf, wcbf,
                                          v2tp, wotbf, bc2);
    qkc_gemm<<<672, 256, 0, stream>>>(encbf, cebf, wcbf, wqbf, wkbf, wotbf,
                                      bq, bk, qbf, kcbf, wc2bf);
    // fused stage-1 (cooperative, grid-wide sync between rowsum and colsum)
    {
        const ushort* a0 = qbf; const ushort* a1 = kcbf;
        float* a2 = rsp; float* a3 = part;
        void* args[] = {(void*)&a0, (void*)&a1, (void*)&a2, (void*)&a3};
        hipLaunchCooperativeKernel((void*)stage1_fused, dim3(16, 4, 8),
                                   dim3(256), args, 0, stream);
    }
    reduce_full_kernel<<<8, 256, 0, stream>>>(part, cs);
    topk_kernel<<<1, 64, 0, stream>>>(cs, idx);
    kv2_proj<<<dim3(4, 2, 2), 256, 0, stream>>>(cebf, idx, wkbf, wvbf, bk, bv,
                                                k2bf, v2tp);
    attn2_fused<<<dim3(64, 4), 512, 0, stream>>>(qbf, k2bf, v2tp, obf);
    proj_ln<<<256, 256, 0, stream>>>(obf, wc2bf, bc2, enc, lng, lnb, out);
    (void)in_sizes; (void)n_in; (void)out_size; (void)ws_size;
}

// Round 18
// 136.105 us; speedup vs baseline: 1.5450x; 1.5450x over previous
//
#include <hip/hip_runtime.h>
#include <hip/hip_bf16.h>

// ContextModule R18: revert R17's cooperative stage-1 (VGPR-spill regression)
// back to R16's split rowsum/colsum pair; keep flattened 672-block qkc grid.
// 9 dispatches, ws 55.6 MB.

typedef short bhalf8 __attribute__((ext_vector_type(8)));   // 8 bf16 = 4 VGPR
typedef float f32x4 __attribute__((ext_vector_type(4)));

#define SCALE 0.08838834764831845f  // 1/sqrt(128)

// ---- ws layout (float offsets) ----
#define OFF_QBF    ((size_t)0)               // qbf bf16 [8192][512]
#define OFF_RB     ((size_t)6193152)         // encbf -> kcbf -> obf bf16 [8192][512]
#define OFF_TMP    ((size_t)8290304)
#define OFF_PART   (OFF_TMP)                 // [256][2000] f32 colsum partials
#define OFF_CS     (OFF_TMP + 1024000)       // cs [2048] f32
#define OFF_IDX    (OFF_TMP + 1026048)       // 128 ints
#define OFF_RSP    (OFF_TMP + 1026176)       // rowsum partials [4096][8] f32
#define OFF_CEBF   ((size_t)12484608)        // ce bf16 [2000][512]
#define OFF_K2BF   ((size_t)13022608)        // k2 bf16 [101][512]
#define OFF_V2TP   ((size_t)13074608)        // v2tp bf16 [4][128][128]
#define OFF_WQBF   ((size_t)13107376)
#define OFF_WKBF   ((size_t)13238448)
#define OFF_WVBF   ((size_t)13369520)
#define OFF_WCBF   ((size_t)13500592)
#define OFF_WOTBF  ((size_t)13631664)
#define OFF_WC2BF  ((size_t)13762736)
#define OFF_BC2    ((size_t)13893808)        // 512
// total 13,894,320 fl = 55.6 MB

__device__ __forceinline__ float bf2f(short u) {
    union { float f; unsigned int i; } x;
    x.i = ((unsigned int)(unsigned short)u) << 16;
    return x.f;
}
__device__ __forceinline__ ushort f2b(float f) {
    union { float f; unsigned int i; } x; x.f = f;
    return (ushort)((x.i + 0x7fff + ((x.i >> 16) & 1)) >> 16);  // RNE
}

// async global->LDS, 16B per lane; LDS dest = wave-uniform base + lane*16
__device__ __forceinline__ void gld16(ushort* lds, const ushort* g) {
    __builtin_amdgcn_global_load_lds(
        (const __attribute__((address_space(1))) unsigned int*)g,
        (__attribute__((address_space(3))) unsigned int*)lds, 16, 0, 0);
}

// ---------------------------------------------------------------------------
// prep: f32->bf16 conversions + v2tp zero + bc2 + wo-transpose, one launch.
// ---------------------------------------------------------------------------
__global__ __launch_bounds__(256) void prep_kernel(
    const float* __restrict__ enc, const float* __restrict__ ce,
    const float* __restrict__ wq, const float* __restrict__ wk,
    const float* __restrict__ wv, const float* __restrict__ wc,
    const float* __restrict__ wo, const float* __restrict__ bo,
    const float* __restrict__ bcb,
    ushort* __restrict__ encbf, ushort* __restrict__ cebf,
    ushort* __restrict__ wqbf, ushort* __restrict__ wkbf,
    ushort* __restrict__ wvbf, ushort* __restrict__ wcbf,
    ushort* __restrict__ v2tp, ushort* __restrict__ wotbf,
    float* __restrict__ bc2)
{
    __shared__ float tile[32][33];
    const int b = blockIdx.x, tid = threadIdx.x;
    const float* s; ushort* d; int n4, base;
    if (b < 4096)      { s = enc; d = encbf; n4 = 1048576; base = b; }
    else if (b < 5096) { s = ce;  d = cebf;  n4 = 256000;  base = b - 4096; }
    else if (b < 5352) { s = wq;  d = wqbf;  n4 = 65536;   base = b - 5096; }
    else if (b < 5608) { s = wk;  d = wkbf;  n4 = 65536;   base = b - 5352; }
    else if (b < 5864) { s = wv;  d = wvbf;  n4 = 65536;   base = b - 5608; }
    else if (b < 6120) { s = wc;  d = wcbf;  n4 = 65536;   base = b - 5864; }
    else if (b < 6152) {
        const int i = (b - 6120) * 256 + tid;          // 8192 uint4
        ((uint4*)v2tp)[i] = make_uint4(0u, 0u, 0u, 0u);
        return;
    } else if (b < 6154) {
        const int dd = (b - 6152) * 256 + tid;
        float acc = bcb[dd];
        const float4* wr = (const float4*)(wc + (size_t)dd * 512);
        const float4* br = (const float4*)bo;
        for (int m4 = 0; m4 < 128; ++m4) {
            const float4 w4 = wr[m4], b4 = br[m4];
            acc += w4.x * b4.x + w4.y * b4.y + w4.z * b4.z + w4.w * b4.w;
        }
        bc2[dd] = acc;
        return;
    } else {
        const int b2 = b - 6154;                       // 256 tiles
        const int bx = (b2 & 15) * 32, by = (b2 >> 4) * 32;
        const int tx = tid & 31, ty = tid >> 5;        // 32x8
        #pragma unroll
        for (int rr = 0; rr < 4; ++rr)
            tile[ty + 8 * rr][tx] = wo[(size_t)(by + ty + 8 * rr) * 512 + bx + tx];
        __syncthreads();
        #pragma unroll
        for (int rr = 0; rr < 4; ++rr)
            wotbf[(size_t)(bx + ty + 8 * rr) * 512 + by + tx] =
                f2b(tile[tx][ty + 8 * rr]);
        return;
    }
    const int i = base * 256 + tid;
    if (i >= n4) return;
    const float4 v = ((const float4*)s)[i];
    ushort4 r;
    r.x = f2b(v.x); r.y = f2b(v.y); r.z = f2b(v.z); r.w = f2b(v.w);
    ((ushort4*)d)[i] = r;
}

// ---------------------------------------------------------------------------
// 64x128 MFMA GEMM body, BK=64, double-buffered, one barrier per K-step.
// ---------------------------------------------------------------------------
__device__ __forceinline__ void stage_ab(
    const ushort* gA, const ushort* gB0, const ushort* gB1, int k0,
    ushort* As, ushort* Bs, int wave)
{
    gld16(As + wave * 512,        gA  + k0);
    gld16(As + 2048 + wave * 512, gA  + k0 + 32);
    gld16(Bs + wave * 512,        gB0 + k0);
    gld16(Bs + 4096 + wave * 512, gB0 + k0 + 32);
    gld16(Bs + 2048 + wave * 512, gB1 + k0);
    gld16(Bs + 6144 + wave * 512, gB1 + k0 + 32);
}

__device__ __forceinline__ void gemm_body_512(
    const ushort* A, const ushort* W, const float* bias, ushort* Cbf,
    int M, int bm, int bn, ushort* As, ushort* Bs, int rowA)
{
    const int tid = threadIdx.x;
    const int wave = tid >> 6, lane = tid & 63;
    const int wm = wave >> 1, wn = wave & 1;
    const int mr = lane & 15, g = lane >> 4;

    f32x4 acc[2][4];
    #pragma unroll
    for (int i = 0; i < 2; ++i)
        #pragma unroll
        for (int j = 0; j < 4; ++j)
            #pragma unroll
            for (int p = 0; p < 4; ++p) acc[i][j][p] = 0.f;

    const int r0 = tid >> 2, c0 = tid & 3;
    const int cA = (c0 ^ (r0 & 3)) * 8;
    const ushort* gA  = A + (size_t)rowA * 512 + cA;
    const ushort* gB0 = W + (size_t)(bn + r0) * 512 + cA;
    const ushort* gB1 = W + (size_t)(bn + r0 + 64) * 512 + cA;

    stage_ab(gA, gB0, gB1, 0, As, Bs, wave);
    for (int k0 = 0; k0 < 512; k0 += 64) {
        const int cur = (k0 >> 6) & 1;
        ushort* Ac = As + cur * 4096;
        ushort* Bc = Bs + cur * 8192;
        __syncthreads();   // drains cur's loads; other buf free
        if (k0 + 64 < 512)
            stage_ab(gA, gB0, gB1, k0 + 64,
                     As + (cur ^ 1) * 4096, Bs + (cur ^ 1) * 8192, wave);
        const int ksw = (g ^ (mr & 3)) << 3;
        #pragma unroll
        for (int h = 0; h < 2; ++h) {
            bhalf8 a[2], b[4];
            #pragma unroll
            for (int i = 0; i < 2; ++i)
                a[i] = *(const bhalf8*)
                    &Ac[h * 2048 + (wm * 32 + i * 16 + mr) * 32 + ksw];
            #pragma unroll
            for (int j = 0; j < 4; ++j)
                b[j] = *(const bhalf8*)
                    &Bc[h * 4096 + (wn * 64 + j * 16 + mr) * 32 + ksw];
            #pragma unroll
            for (int i = 0; i < 2; ++i)
                #pragma unroll
                for (int j = 0; j < 4; ++j)
                    acc[i][j] = __builtin_amdgcn_mfma_f32_16x16x32_bf16(
                        a[i], b[j], acc[i][j], 0, 0, 0);
        }
    }

    #pragma unroll
    for (int i = 0; i < 2; ++i) {
        #pragma unroll
        for (int j = 0; j < 4; ++j) {
            const int gn = bn + wn * 64 + j * 16 + mr;
            const float bb = bias ? bias[gn] : 0.f;
            #pragma unroll
            for (int p = 0; p < 4; ++p) {
                const int gm = bm + wm * 32 + i * 16 + g * 4 + p;
                if (gm >= M) continue;
                Cbf[(size_t)gm * 512 + gn] = f2b(acc[i][j][p] + bb);
            }
        }
    }
}

// q-proj / kc-proj / Wc2 in one FLAT launch: 672 blocks, no empty blocks.
__global__ __launch_bounds__(256) void qkc_gemm(
    const ushort* __restrict__ encbf, const ushort* __restrict__ cebf,
    const ushort* __restrict__ wcbf,
    const ushort* __restrict__ wqbf, const ushort* __restrict__ wkbf,
    const ushort* __restrict__ wotbf,
    const float* __restrict__ bq, const float* __restrict__ bk,
    ushort* __restrict__ qbf, ushort* __restrict__ kcbf,
    ushort* __restrict__ wc2bf)
{
    __shared__ __align__(16) ushort As[2 * 64 * 64];
    __shared__ __align__(16) ushort Bs[2 * 128 * 64];
    const int bid = blockIdx.x;
    int z, x, y;
    if (bid < 512)      { z = 0; x = bid & 3; y = bid >> 2; }
    else if (bid < 640) { z = 1; x = (bid - 512) & 3; y = (bid - 512) >> 2; }
    else                { z = 2; x = (bid - 640) & 3; y = (bid - 640) >> 2; }
    const ushort* A = (z == 0) ? encbf : (z == 1) ? cebf : wcbf;
    const ushort* W = (z == 0) ? wqbf : (z == 1) ? wkbf : wotbf;
    const float* bias = (z == 0) ? bq : (z == 1) ? bk : nullptr;
    ushort* C = (z == 0) ? qbf : (z == 1) ? kcbf : wc2bf;
    const int M = (z == 0) ? 8192 : (z == 1) ? 2000 : 512;
    const int bm = y * 64;
    const int rowA = min(bm + (threadIdx.x >> 2), M - 1);
    gemm_body_512(A, W, bias, C, M, bm, x * 128, As, Bs, rowA);
}

// ---------------------------------------------------------------------------
// Stage-1 machinery. grid (16 m, 4 h, 8 nc), 2 tiles/block, dbuf Ks (64KB).
// ---------------------------------------------------------------------------
__device__ __forceinline__ void stage_ktile(
    ushort* Ks, const ushort* kcbf, int nt, int h, int w, int lane)
{
    #pragma unroll
    for (int it = 0; it < 8; ++it) {
        const int u = it * 256 + (w << 6) + lane;   // 0..2047
        const int nl = u >> 4, c = u & 15;
        gld16(Ks + (size_t)(it * 256 + (w << 6)) * 8,
              kcbf + (size_t)(nt * 128 + nl) * 512 + (h << 7)
                   + ((c ^ (nl & 7)) << 3));
    }
}

__device__ __forceinline__ void score_tile(
    const ushort* Ks, const bhalf8* aq, int mr, int g, f32x4* sacc)
{
    #pragma unroll
    for (int jn = 0; jn < 8; ++jn)
        #pragma unroll
        for (int p = 0; p < 4; ++p) sacc[jn][p] = 0.f;
    #pragma unroll
    for (int kd = 0; kd < 4; ++kd) {
        #pragma unroll
        for (int jn = 0; jn < 8; ++jn) {
            const int n = (jn << 4) + mr;
            const bhalf8 bk = *(const bhalf8*)
                &Ks[(n << 7) + ((((kd << 2) + g) ^ (n & 7)) << 3)];
            sacc[jn] = __builtin_amdgcn_mfma_f32_16x16x32_bf16(
                aq[kd], bk, sacc[jn], 0, 0, 0);
        }
    }
}

// A: rowsum partials. grid (16,4,8); rsp[(h*1024+row)*8 + nc].
__global__ __launch_bounds__(256) void rowsum_part(
    const ushort* __restrict__ qb, const ushort* __restrict__ kcbf,
    float* __restrict__ rsp)
{
    __shared__ __align__(16) ushort Ks[2 * 128 * 128];
    const int tid = threadIdx.x, w = tid >> 6, lane = tid & 63;
    const int mr = lane & 15, g = lane >> 4;
    const int h = blockIdx.y, nc = blockIdx.z;
    const int bm = blockIdx.x * 64;

    const ushort* qrow = qb + (size_t)(bm + (w << 4) + mr) * 512 + (h << 7);
    bhalf8 aq[4];
    #pragma unroll
    for (int kd = 0; kd < 4; ++kd)
        aq[kd] = *(const bhalf8*)(qrow + (g << 3) + (kd << 5));

    const int nt0 = nc * 2, nt1 = nc * 2 + 1;
    stage_ktile(Ks, kcbf, nt0, h, w, lane);
    __syncthreads();                                 // tile0 ready
    stage_ktile(Ks + 16384, kcbf, nt1, h, w, lane);  // tile1 in flight

    float rsl[4] = {0.f, 0.f, 0.f, 0.f};
    f32x4 sacc[8];
    score_tile(Ks, aq, mr, g, sacc);
    #pragma unroll
    for (int jn = 0; jn < 8; ++jn) {
        const bool valid = nt0 * 128 + (jn << 4) + mr < 2000;
        #pragma unroll
        for (int p = 0; p < 4; ++p)
            rsl[p] += valid ? __expf(sacc[jn][p] * SCALE) : 0.f;
    }
    __syncthreads();                                 // tile1 ready
    score_tile(Ks + 16384, aq, mr, g, sacc);
    #pragma unroll
    for (int jn = 0; jn < 8; ++jn) {
        const bool valid = nt1 * 128 + (jn << 4) + mr < 2000;
        #pragma unroll
        for (int p = 0; p < 4; ++p)
            rsl[p] += valid ? __expf(sacc[jn][p] * SCALE) : 0.f;
    }

    #pragma unroll
    for (int off = 1; off <= 8; off <<= 1)
        #pragma unroll
        for (int p = 0; p < 4; ++p)
            rsl[p] += __shfl_xor(rsl[p], off);
    if (mr == 0) {
        #pragma unroll
        for (int p = 0; p < 4; ++p) {
            const int row = (h << 10) + bm + (w << 4) + (g << 2) + p;
            rsp[(size_t)row * 8 + nc] = rsl[p];
        }
    }
}

// B: colsum partials. Same grid; part[slot][n], slot=((h*16+m)<<2)+w.
__global__ __launch_bounds__(256) void colsum_part(
    const ushort* __restrict__ qb, const ushort* __restrict__ kcbf,
    const float* __restrict__ rsp, float* __restrict__ part)
{
    __shared__ __align__(16) ushort Ks[2 * 128 * 128];
    const int tid = threadIdx.x, w = tid >> 6, lane = tid & 63;
    const int mr = lane & 15, g = lane >> 4;
    const int h = blockIdx.y, nc = blockIdx.z;
    const int bm = blockIdx.x * 64;
    const int slot = ((h * 16 + blockIdx.x) << 2) + w;

    const ushort* qrow = qb + (size_t)(bm + (w << 4) + mr) * 512 + (h << 7);
    bhalf8 aq[4];
    #pragma unroll
    for (int kd = 0; kd < 4; ++kd)
        aq[kd] = *(const bhalf8*)(qrow + (g << 3) + (kd << 5));

    float inv[4];
    #pragma unroll
    for (int p = 0; p < 4; ++p) {
        const int row = (h << 10) + bm + (w << 4) + (g << 2) + p;
        const float4 ra = *(const float4*)(rsp + (size_t)row * 8);
        const float4 rb = *(const float4*)(rsp + (size_t)row * 8 + 4);
        inv[p] = 1.f / (ra.x + ra.y + ra.z + ra.w + rb.x + rb.y + rb.z + rb.w);
    }

    const int nt0 = nc * 2, nt1 = nc * 2 + 1;
    stage_ktile(Ks, kcbf, nt0, h, w, lane);
    __syncthreads();
    stage_ktile(Ks + 16384, kcbf, nt1, h, w, lane);

    f32x4 sacc[8];
    #pragma unroll
    for (int t = 0; t < 2; ++t) {
        if (t == 1) __syncthreads();                 // tile1 ready
        const int nt = t ? nt1 : nt0;
        score_tile(t ? Ks + 16384 : Ks, aq, mr, g, sacc);
        #pragma unroll
        for (int jn = 0; jn < 8; ++jn) {
            const int n = nt * 128 + (jn << 4) + mr;
            const bool valid = n < 2000;
            float cv = 0.f;
            #pragma unroll
            for (int p = 0; p < 4; ++p)
                cv += valid ? __expf(sacc[jn][p] * SCALE) * inv[p] : 0.f;
            cv += __shfl_xor(cv, 16);
            cv += __shfl_xor(cv, 32);   // sum over the wave's 16 rows
            if (g == 0 && valid) part[(size_t)slot * 2000 + n] = cv;
        }
    }
}

// FULL reduction part[256][2000] -> cs[2000]; grid (8), 256 thr.
__global__ __launch_bounds__(256) void reduce_full_kernel(
    const float* __restrict__ part, float* __restrict__ cs)
{
    const int n = blockIdx.x * 256 + threadIdx.x;
    if (n >= 2000) return;
    float s = 0.f;
    for (int sl = 0; sl < 256; ++sl) s += part[(size_t)sl * 2000 + n];
    cs[n] = s;
}

// ---------------------------------------------------------------------------
// Top-101 of 2000 via MSB-first radix-select (ballot/popcount).
// ---------------------------------------------------------------------------
__global__ void topk_kernel(const float* __restrict__ cs,
                            int* __restrict__ idx)
{
    const int lane = threadIdx.x;   // block = 64
    const unsigned long long below = (1ull << lane) - 1ull;

    unsigned key[32];
    #pragma unroll
    for (int i = 0; i < 32; ++i) {
        const int n = lane + 64 * i;
        const float s = (n < 2000) ? cs[n] : -1e30f;
        const unsigned u = __float_as_uint(s);
        key[i] = u ^ ((unsigned)((int)u >> 31) | 0x80000000u);
    }

    unsigned prefix = 0;
    int remaining = 101;
    for (int b = 31; b >= 0; --b) {
        const unsigned tgt = (prefix << 1) | 1u;
        int cnt = 0;
        #pragma unroll
        for (int i = 0; i < 32; ++i)
            cnt += (int)__popcll(__ballot((key[i] >> b) == tgt));
        if (cnt >= remaining) prefix = tgt;
        else { remaining -= cnt; prefix = prefix << 1; }
    }
    const unsigned T = prefix;

    int base = 0;
    #pragma unroll
    for (int i = 0; i < 32; ++i) {
        const unsigned long long m = __ballot(key[i] > T);
        if (key[i] > T) idx[base + (int)__popcll(m & below)] = lane + 64 * i;
        base += (int)__popcll(m);
    }
    int r = remaining;
    #pragma unroll
    for (int i = 0; i < 32; ++i) {
        const unsigned long long m = __ballot(key[i] == T);
        const int cb = (int)__popcll(m & below);
        if (key[i] == T && cb < r) idx[base + cb] = lane + 64 * i;
        const int take = min(r, (int)__popcll(m));
        base += take; r -= take;
    }
}

// ---------------------------------------------------------------------------
// Fused k2/v2 projections with inline gather, dbuf BK=64 (z=0 k2; z=1 v2tp).
// ---------------------------------------------------------------------------
__global__ __launch_bounds__(256) void kv2_proj(
    const ushort* __restrict__ cebf, const int* __restrict__ idxbuf,
    const ushort* __restrict__ wkbf, const ushort* __restrict__ wvbf,
    const float* __restrict__ bk, const float* __restrict__ bv,
    ushort* __restrict__ k2bf, ushort* __restrict__ v2tp)
{
    __shared__ __align__(16) ushort As[2 * 64 * 64];
    __shared__ __align__(16) ushort Bs[2 * 128 * 64];
    const int z = blockIdx.z;
    const ushort* W = z ? wvbf : wkbf;
    const float* bias = z ? bv : bk;
    const int tid = threadIdx.x;
    const int wave = tid >> 6, lane = tid & 63;
    const int wm = wave >> 1, wn = wave & 1;
    const int mr = lane & 15, g = lane >> 4;
    const int bm = blockIdx.y * 64, bn = blockIdx.x * 128;

    f32x4 acc[2][4];
    #pragma unroll
    for (int i = 0; i < 2; ++i)
        #pragma unroll
        for (int j = 0; j < 4; ++j)
            #pragma unroll
            for (int p = 0; p < 4; ++p) acc[i][j][p] = 0.f;

    const int r0 = tid >> 2, c0 = tid & 3;
    const int cA = (c0 ^ (r0 & 3)) * 8;
    const int rA  = min(bm + r0, 100);
    const int srcrow = idxbuf[rA];               // inline gather
    const ushort* gA  = cebf + (size_t)srcrow * 512 + cA;
    const ushort* gB0 = W + (size_t)(bn + r0) * 512 + cA;
    const ushort* gB1 = W + (size_t)(bn + r0 + 64) * 512 + cA;

    stage_ab(gA, gB0, gB1, 0, As, Bs, wave);
    for (int k0 = 0; k0 < 512; k0 += 64) {
        const int cur = (k0 >> 6) & 1;
        ushort* Ac = As + cur * 4096;
        ushort* Bc = Bs + cur * 8192;
        __syncthreads();
        if (k0 + 64 < 512)
            stage_ab(gA, gB0, gB1, k0 + 64,
                     As + (cur ^ 1) * 4096, Bs + (cur ^ 1) * 8192, wave);
        const int ksw = (g ^ (mr & 3)) << 3;
        #pragma unroll
        for (int h = 0; h < 2; ++h) {
            bhalf8 a[2], b[4];
            #pragma unroll
            for (int i = 0; i < 2; ++i)
                a[i] = *(const bhalf8*)
                    &Ac[h * 2048 + (wm * 32 + i * 16 + mr) * 32 + ksw];
            #pragma unroll
            for (int j = 0; j < 4; ++j)
                b[j] = *(const bhalf8*)
                    &Bc[h * 4096 + (wn * 64 + j * 16 + mr) * 32 + ksw];
            #pragma unroll
            for (int i = 0; i < 2; ++i)
                #pragma unroll
                for (int j = 0; j < 4; ++j)
                    acc[i][j] = __builtin_amdgcn_mfma_f32_16x16x32_bf16(
                        a[i], b[j], acc[i][j], 0, 0, 0);
        }
    }

    #pragma unroll
    for (int i = 0; i < 2; ++i) {
        #pragma unroll
        for (int j = 0; j < 4; ++j) {
            const int gn = bn + wn * 64 + j * 16 + mr;
            const float bb = bias[gn];
            #pragma unroll
            for (int p = 0; p < 4; ++p) {
                const int gm = bm + wm * 32 + i * 16 + g * 4 + p;
                if (gm >= 101) continue;
                const ushort v = f2b(acc[i][j][p] + bb);
                if (z == 0) k2bf[(size_t)gm * 512 + gn] = v;
                else        v2tp[(size_t)gn * 128 + gm] = v;
            }
        }
    }
}

// ---------------------------------------------------------------------------
// Fused stage-2 attention, 8 waves x 128 rows per block. grid (64, 4).
// ---------------------------------------------------------------------------
__global__ __launch_bounds__(512) void attn2_fused(
    const ushort* __restrict__ qb, const ushort* __restrict__ k2bf,
    const ushort* __restrict__ v2tp, ushort* __restrict__ obf)
{
    __shared__ __align__(16) ushort K2s[128 * 128];
    __shared__ __align__(16) ushort V2s[128 * 128];
    __shared__ __align__(16) ushort Ps[8 * 16 * 128];
    const int tid = threadIdx.x, w = tid >> 6, lane = tid & 63;
    const int mr = lane & 15, g = lane >> 4;
    const int h = blockIdx.y;
    const int bm = blockIdx.x * 128;

    #pragma unroll
    for (int it = 0; it < 4; ++it) {
        const int cl = tid + 512 * it;      // 0..2047
        const int n = cl >> 4, c = cl & 15;
        uint4 kv = make_uint4(0u, 0u, 0u, 0u);
        if (n < 101)
            kv = *(const uint4*)(k2bf + (size_t)n * 512 + h * 128 + c * 8);
        *(uint4*)&K2s[(n << 7) + ((c ^ (n & 7)) << 3)] = kv;
        const uint4 vv = *(const uint4*)(v2tp + (((size_t)h << 7) + n) * 128 + c * 8);
        *(uint4*)&V2s[(n << 7) + ((c ^ (n & 7)) << 3)] = vv;
    }
    __syncthreads();

    f32x4 sacc[8];
    #pragma unroll
    for (int jn = 0; jn < 8; ++jn)
        #pragma unroll
        for (int p = 0; p < 4; ++p) sacc[jn][p] = 0.f;
    const ushort* qrow = qb + (size_t)(bm + (w << 4) + mr) * 512 + (h << 7);
    #pragma unroll
    for (int kd = 0; kd < 4; ++kd) {
        const bhalf8 aq = *(const bhalf8*)(qrow + (g << 3) + (kd << 5));
        #pragma unroll
        for (int jn = 0; jn < 8; ++jn) {
            const int n = (jn << 4) + mr;
            const bhalf8 bk = *(const bhalf8*)
                &K2s[(n << 7) + ((((kd << 2) + g) ^ (n & 7)) << 3)];
            sacc[jn] = __builtin_amdgcn_mfma_f32_16x16x32_bf16(aq, bk, sacc[jn], 0, 0, 0);
        }
    }

    float mrow[4] = {-1e30f, -1e30f, -1e30f, -1e30f};
    #pragma unroll
    for (int jn = 0; jn < 8; ++jn) {
        const bool valid = (jn < 6) || (jn == 6 && mr < 5);
        #pragma unroll
        for (int p = 0; p < 4; ++p) {
            const float s = valid ? sacc[jn][p] * SCALE : -1e30f;
            sacc[jn][p] = s;
            mrow[p] = fmaxf(mrow[p], s);
        }
    }
    #pragma unroll
    for (int off = 1; off <= 8; off <<= 1)
        #pragma unroll
        for (int p = 0; p < 4; ++p)
            mrow[p] = fmaxf(mrow[p], __shfl_xor(mrow[p], off));
    float srow[4] = {0.f, 0.f, 0.f, 0.f};
    #pragma unroll
    for (int jn = 0; jn < 8; ++jn)
        #pragma unroll
        for (int p = 0; p < 4; ++p) {
            const float e = __expf(sacc[jn][p] - mrow[p]);
            sacc[jn][p] = e;
            srow[p] += e;
        }
    #pragma unroll
    for (int off = 1; off <= 8; off <<= 1)
        #pragma unroll
        for (int p = 0; p < 4; ++p)
            srow[p] += __shfl_xor(srow[p], off);
    float inv[4];
    #pragma unroll
    for (int p = 0; p < 4; ++p) inv[p] = 1.f / srow[p];

    ushort* pw = Ps + (w << 11);
    #pragma unroll
    for (int jn = 0; jn < 8; ++jn) {
        const int cb = (jn << 1) + (mr >> 3);
        #pragma unroll
        for (int p = 0; p < 4; ++p) {
            const int r = (g << 2) + p;
            pw[(r << 7) + ((cb ^ (r & 7)) << 3) + (mr & 7)] =
                f2b(sacc[jn][p] * inv[p]);
        }
    }

    f32x4 oacc[8];
    #pragma unroll
    for (int jd = 0; jd < 8; ++jd)
        #pragma unroll
        for (int p = 0; p < 4; ++p) oacc[jd][p] = 0.f;
    #pragma unroll
    for (int kn = 0; kn < 4; ++kn) {
        const int ck = (kn << 2) + g;
        const bhalf8 ap = *(const bhalf8*)
            &pw[(mr << 7) + ((ck ^ (mr & 7)) << 3)];
        #pragma unroll
        for (int jd = 0; jd < 8; ++jd) {
            const int d = (jd << 4) + mr;
            const bhalf8 bv = *(const bhalf8*)
                &V2s[(d << 7) + ((ck ^ (d & 7)) << 3)];
            oacc[jd] = __builtin_amdgcn_mfma_f32_16x16x32_bf16(ap, bv, oacc[jd], 0, 0, 0);
        }
    }

    #pragma unroll
    for (int jd = 0; jd < 8; ++jd)
        #pragma unroll
        for (int p = 0; p < 4; ++p) {
            const int row = bm + (w << 4) + (g << 2) + p;
            obf[(size_t)row * 512 + (h << 7) + (jd << 4) + mr] = f2b(oacc[jd][p]);
        }
}

// ---------------------------------------------------------------------------
// Fused final projection + residual + LayerNorm, dbuf BK=64.
// ---------------------------------------------------------------------------
__device__ __forceinline__ void pl_stage(
    const ushort* gA, const ushort* gB, int k0,
    ushort* Asb, ushort* Bsb, int w)
{
    if (w < 2) {
        gld16(Asb + w * 512,        gA + k0);
        gld16(Asb + 1024 + w * 512, gA + k0 + 32);
    }
    #pragma unroll
    for (int r = 0; r < 8; ++r) {
        const int nb = r * 4 + w;              // 0..31 groups of 16 rows
        gld16(Bsb + nb * 512,         gB + nb * 8192 + k0);
        gld16(Bsb + 16384 + nb * 512, gB + nb * 8192 + k0 + 32);
    }
}

__global__ __launch_bounds__(256) void proj_ln(
    const ushort* __restrict__ obf, const ushort* __restrict__ wc2bf,
    const float* __restrict__ bc2, const float* __restrict__ enc,
    const float* __restrict__ gw, const float* __restrict__ bta,
    float* __restrict__ out)
{
    __shared__ __align__(16) ushort As[2 * 2048];
    __shared__ __align__(16) ushort Bs[2 * 32768];
    __shared__ float red1[2][32], red2[2][32];
    const int tid = threadIdx.x, w = tid >> 6, lane = tid & 63;
    const int mr = lane & 15, gq = lane >> 4;
    const int rh = w & 1, ch = w >> 1;
    const int bm = blockIdx.x * 32;

    f32x4 acc[16];
    #pragma unroll
    for (int j = 0; j < 16; ++j)
        #pragma unroll
        for (int p = 0; p < 4; ++p) acc[j][p] = 0.f;

    const int lr = lane >> 2, lc = lane & 3;
    const int swc = (lc ^ (lr & 3)) * 8;
    const ushort* gA = obf + (size_t)(bm + ((w & 1) << 4) + lr) * 512 + swc;
    const ushort* gB = wc2bf + (size_t)lr * 512 + swc;

    pl_stage(gA, gB, 0, As, Bs, w);
    for (int k0 = 0; k0 < 512; k0 += 64) {
        const int cur = (k0 >> 6) & 1;
        ushort* Ac = As + cur * 2048;
        ushort* Bc = Bs + cur * 32768;
        __syncthreads();
        if (k0 + 64 < 512)
            pl_stage(gA, gB, k0 + 64,
                     As + (cur ^ 1) * 2048, Bs + (cur ^ 1) * 32768, w);
        const int ksw = (gq ^ (mr & 3)) << 3;
        #pragma unroll
        for (int h = 0; h < 2; ++h) {
            const bhalf8 a = *(const bhalf8*)
                &Ac[h * 1024 + (((rh << 4) + mr) << 5) + ksw];
            #pragma unroll
            for (int j = 0; j < 16; ++j) {
                const int n = (ch << 8) + (j << 4) + mr;
                const bhalf8 b = *(const bhalf8*)
                    &Bc[h * 16384 + (n << 5) + ksw];
                acc[j] = __builtin_amdgcn_mfma_f32_16x16x32_bf16(a, b, acc[j], 0, 0, 0);
            }
        }
    }

    float s1[4] = {0.f, 0.f, 0.f, 0.f}, s2[4] = {0.f, 0.f, 0.f, 0.f};
    #pragma unroll
    for (int j = 0; j < 16; ++j) {
        const int gcol = (ch << 8) + (j << 4) + mr;
        const float bb = bc2[gcol];
        #pragma unroll
        for (int p = 0; p < 4; ++p) {
            const int grow = bm + (rh << 4) + (gq << 2) + p;
            const float x = acc[j][p] + bb + enc[(size_t)grow * 512 + gcol];
            acc[j][p] = x;
            s1[p] += x;
            s2[p] += x * x;
        }
    }
    #pragma unroll
    for (int off = 1; off <= 8; off <<= 1)
        #pragma unroll
        for (int p = 0; p < 4; ++p) {
            s1[p] += __shfl_xor(s1[p], off);
            s2[p] += __shfl_xor(s2[p], off);
        }
    if (mr == 0) {
        #pragma unroll
        for (int p = 0; p < 4; ++p) {
            red1[ch][(rh << 4) + (gq << 2) + p] = s1[p];
            red2[ch][(rh << 4) + (gq << 2) + p] = s2[p];
        }
    }
    __syncthreads();
    float mu[4], rstd[4];
    #pragma unroll
    for (int p = 0; p < 4; ++p) {
        const int ri = (rh << 4) + (gq << 2) + p;
        const float t1 = red1[0][ri] + red1[1][ri];
        const float t2 = red2[0][ri] + red2[1][ri];
        const float m = t1 * (1.f / 512.f);
        mu[p] = m;
        rstd[p] = rsqrtf(t2 * (1.f / 512.f) - m * m + 1e-5f);
    }
    #pragma unroll
    for (int j = 0; j < 16; ++j) {
        const int gcol = (ch << 8) + (j << 4) + mr;
        const float gg = gw[gcol], bb = bta[gcol];
        #pragma unroll
        for (int p = 0; p < 4; ++p) {
            const int grow = bm + (rh << 4) + (gq << 2) + p;
            out[(size_t)grow * 512 + gcol] = (acc[j][p] - mu[p]) * rstd[p] * gg + bb;
        }
    }
}

extern "C" void kernel_launch(void* const* d_in, const int* in_sizes, int n_in,
                              void* d_out, int out_size, void* d_ws, size_t ws_size,
                              hipStream_t stream)
{
    const float* ce  = (const float*)d_in[0];
    const float* enc = (const float*)d_in[1];
    const float* wq  = (const float*)d_in[2];
    const float* bq  = (const float*)d_in[3];
    const float* wk  = (const float*)d_in[4];
    const float* bk  = (const float*)d_in[5];
    const float* wv  = (const float*)d_in[6];
    const float* bv  = (const float*)d_in[7];
    const float* wo  = (const float*)d_in[8];
    const float* bo  = (const float*)d_in[9];
    const float* wc  = (const float*)d_in[10];
    const float* bcb = (const float*)d_in[11];
    const float* lng = (const float*)d_in[12];
    const float* lnb = (const float*)d_in[13];
    float* ws  = (float*)d_ws;
    float* out = (float*)d_out;

    ushort* qbf    = (ushort*)(ws + OFF_QBF);
    ushort* encbf  = (ushort*)(ws + OFF_RB);     // -> kcbf -> obf
    ushort* kcbf   = (ushort*)(ws + OFF_RB);
    ushort* obf    = (ushort*)(ws + OFF_RB);
    float*  part   = ws + OFF_PART;
    float*  cs     = ws + OFF_CS;
    int*    idx    = (int*)(ws + OFF_IDX);
    float*  rsp    = ws + OFF_RSP;
    ushort* cebf   = (ushort*)(ws + OFF_CEBF);
    ushort* k2bf   = (ushort*)(ws + OFF_K2BF);
    ushort* v2tp   = (ushort*)(ws + OFF_V2TP);
    ushort* wqbf   = (ushort*)(ws + OFF_WQBF);
    ushort* wkbf   = (ushort*)(ws + OFF_WKBF);
    ushort* wvbf   = (ushort*)(ws + OFF_WVBF);
    ushort* wcbf   = (ushort*)(ws + OFF_WCBF);
    ushort* wotbf  = (ushort*)(ws + OFF_WOTBF);
    ushort* wc2bf  = (ushort*)(ws + OFF_WC2BF);
    float*  bc2    = ws + OFF_BC2;

    prep_kernel<<<6410, 256, 0, stream>>>(enc, ce, wq, wk, wv, wc, wo, bo, bcb,
                                          encbf, cebf, wqbf, wkbf, wvbf, wcbf,
                                          v2tp, wotbf, bc2);
    qkc_gemm<<<672, 256, 0, stream>>>(encbf, cebf, wcbf, wqbf, wkbf, wotbf,
                                      bq, bk, qbf, kcbf, wc2bf);
    rowsum_part<<<dim3(16, 4, 8), 256, 0, stream>>>(qbf, kcbf, rsp);
    colsum_part<<<dim3(16, 4, 8), 256, 0, stream>>>(qbf, kcbf, rsp, part);
    reduce_full_kernel<<<8, 256, 0, stream>>>(part, cs);
    topk_kernel<<<1, 64, 0, stream>>>(cs, idx);
    kv2_proj<<<dim3(4, 2, 2), 256, 0, stream>>>(cebf, idx, wkbf, wvbf, bk, bv,
                                                k2bf, v2tp);
    attn2_fused<<<dim3(64, 4), 512, 0, stream>>>(qbf, k2bf, v2tp, obf);
    proj_ln<<<256, 256, 0, stream>>>(obf, wc2bf, bc2, enc, lng, lnb, out);
    (void)in_sizes; (void)n_in; (void)out_size; (void)ws_size;
}

// Round 19
// 131.506 us; speedup vs baseline: 1.5990x; 1.0350x over previous
//
#include <hip/hip_runtime.h>
#include <hip/hip_bf16.h>

// ContextModule R19: proj_ln -> 8 waves (2/SIMD, was 1); qkc z=0 y-major
// block order (A-tile XCD affinity). 9 dispatches, ws 55.6 MB.

typedef short bhalf8 __attribute__((ext_vector_type(8)));   // 8 bf16 = 4 VGPR
typedef float f32x4 __attribute__((ext_vector_type(4)));

#define SCALE 0.08838834764831845f  // 1/sqrt(128)

// ---- ws layout (float offsets) ----
#define OFF_QBF    ((size_t)0)               // qbf bf16 [8192][512]
#define OFF_RB     ((size_t)6193152)         // encbf -> kcbf -> obf bf16 [8192][512]
#define OFF_TMP    ((size_t)8290304)
#define OFF_PART   (OFF_TMP)                 // [256][2000] f32 colsum partials
#define OFF_CS     (OFF_TMP + 1024000)       // cs [2048] f32
#define OFF_IDX    (OFF_TMP + 1026048)       // 128 ints
#define OFF_RSP    (OFF_TMP + 1026176)       // rowsum partials [4096][8] f32
#define OFF_CEBF   ((size_t)12484608)        // ce bf16 [2000][512]
#define OFF_K2BF   ((size_t)13022608)        // k2 bf16 [101][512]
#define OFF_V2TP   ((size_t)13074608)        // v2tp bf16 [4][128][128]
#define OFF_WQBF   ((size_t)13107376)
#define OFF_WKBF   ((size_t)13238448)
#define OFF_WVBF   ((size_t)13369520)
#define OFF_WCBF   ((size_t)13500592)
#define OFF_WOTBF  ((size_t)13631664)
#define OFF_WC2BF  ((size_t)13762736)
#define OFF_BC2    ((size_t)13893808)        // 512
// total 13,894,320 fl = 55.6 MB

__device__ __forceinline__ float bf2f(short u) {
    union { float f; unsigned int i; } x;
    x.i = ((unsigned int)(unsigned short)u) << 16;
    return x.f;
}
__device__ __forceinline__ ushort f2b(float f) {
    union { float f; unsigned int i; } x; x.f = f;
    return (ushort)((x.i + 0x7fff + ((x.i >> 16) & 1)) >> 16);  // RNE
}

// async global->LDS, 16B per lane; LDS dest = wave-uniform base + lane*16
__device__ __forceinline__ void gld16(ushort* lds, const ushort* g) {
    __builtin_amdgcn_global_load_lds(
        (const __attribute__((address_space(1))) unsigned int*)g,
        (__attribute__((address_space(3))) unsigned int*)lds, 16, 0, 0);
}

// ---------------------------------------------------------------------------
// prep: f32->bf16 conversions + v2tp zero + bc2 + wo-transpose, one launch.
// ---------------------------------------------------------------------------
__global__ __launch_bounds__(256) void prep_kernel(
    const float* __restrict__ enc, const float* __restrict__ ce,
    const float* __restrict__ wq, const float* __restrict__ wk,
    const float* __restrict__ wv, const float* __restrict__ wc,
    const float* __restrict__ wo, const float* __restrict__ bo,
    const float* __restrict__ bcb,
    ushort* __restrict__ encbf, ushort* __restrict__ cebf,
    ushort* __restrict__ wqbf, ushort* __restrict__ wkbf,
    ushort* __restrict__ wvbf, ushort* __restrict__ wcbf,
    ushort* __restrict__ v2tp, ushort* __restrict__ wotbf,
    float* __restrict__ bc2)
{
    __shared__ float tile[32][33];
    const int b = blockIdx.x, tid = threadIdx.x;
    const float* s; ushort* d; int n4, base;
    if (b < 4096)      { s = enc; d = encbf; n4 = 1048576; base = b; }
    else if (b < 5096) { s = ce;  d = cebf;  n4 = 256000;  base = b - 4096; }
    else if (b < 5352) { s = wq;  d = wqbf;  n4 = 65536;   base = b - 5096; }
    else if (b < 5608) { s = wk;  d = wkbf;  n4 = 65536;   base = b - 5352; }
    else if (b < 5864) { s = wv;  d = wvbf;  n4 = 65536;   base = b - 5608; }
    else if (b < 6120) { s = wc;  d = wcbf;  n4 = 65536;   base = b - 5864; }
    else if (b < 6152) {
        const int i = (b - 6120) * 256 + tid;          // 8192 uint4
        ((uint4*)v2tp)[i] = make_uint4(0u, 0u, 0u, 0u);
        return;
    } else if (b < 6154) {
        const int dd = (b - 6152) * 256 + tid;
        float acc = bcb[dd];
        const float4* wr = (const float4*)(wc + (size_t)dd * 512);
        const float4* br = (const float4*)bo;
        for (int m4 = 0; m4 < 128; ++m4) {
            const float4 w4 = wr[m4], b4 = br[m4];
            acc += w4.x * b4.x + w4.y * b4.y + w4.z * b4.z + w4.w * b4.w;
        }
        bc2[dd] = acc;
        return;
    } else {
        const int b2 = b - 6154;                       // 256 tiles
        const int bx = (b2 & 15) * 32, by = (b2 >> 4) * 32;
        const int tx = tid & 31, ty = tid >> 5;        // 32x8
        #pragma unroll
        for (int rr = 0; rr < 4; ++rr)
            tile[ty + 8 * rr][tx] = wo[(size_t)(by + ty + 8 * rr) * 512 + bx + tx];
        __syncthreads();
        #pragma unroll
        for (int rr = 0; rr < 4; ++rr)
            wotbf[(size_t)(bx + ty + 8 * rr) * 512 + by + tx] =
                f2b(tile[tx][ty + 8 * rr]);
        return;
    }
    const int i = base * 256 + tid;
    if (i >= n4) return;
    const float4 v = ((const float4*)s)[i];
    ushort4 r;
    r.x = f2b(v.x); r.y = f2b(v.y); r.z = f2b(v.z); r.w = f2b(v.w);
    ((ushort4*)d)[i] = r;
}

// ---------------------------------------------------------------------------
// 64x128 MFMA GEMM body, BK=64, double-buffered, one barrier per K-step.
// ---------------------------------------------------------------------------
__device__ __forceinline__ void stage_ab(
    const ushort* gA, const ushort* gB0, const ushort* gB1, int k0,
    ushort* As, ushort* Bs, int wave)
{
    gld16(As + wave * 512,        gA  + k0);
    gld16(As + 2048 + wave * 512, gA  + k0 + 32);
    gld16(Bs + wave * 512,        gB0 + k0);
    gld16(Bs + 4096 + wave * 512, gB0 + k0 + 32);
    gld16(Bs + 2048 + wave * 512, gB1 + k0);
    gld16(Bs + 6144 + wave * 512, gB1 + k0 + 32);
}

__device__ __forceinline__ void gemm_body_512(
    const ushort* A, const ushort* W, const float* bias, ushort* Cbf,
    int M, int bm, int bn, ushort* As, ushort* Bs, int rowA)
{
    const int tid = threadIdx.x;
    const int wave = tid >> 6, lane = tid & 63;
    const int wm = wave >> 1, wn = wave & 1;
    const int mr = lane & 15, g = lane >> 4;

    f32x4 acc[2][4];
    #pragma unroll
    for (int i = 0; i < 2; ++i)
        #pragma unroll
        for (int j = 0; j < 4; ++j)
            #pragma unroll
            for (int p = 0; p < 4; ++p) acc[i][j][p] = 0.f;

    const int r0 = tid >> 2, c0 = tid & 3;
    const int cA = (c0 ^ (r0 & 3)) * 8;
    const ushort* gA  = A + (size_t)rowA * 512 + cA;
    const ushort* gB0 = W + (size_t)(bn + r0) * 512 + cA;
    const ushort* gB1 = W + (size_t)(bn + r0 + 64) * 512 + cA;

    stage_ab(gA, gB0, gB1, 0, As, Bs, wave);
    for (int k0 = 0; k0 < 512; k0 += 64) {
        const int cur = (k0 >> 6) & 1;
        ushort* Ac = As + cur * 4096;
        ushort* Bc = Bs + cur * 8192;
        __syncthreads();   // drains cur's loads; other buf free
        if (k0 + 64 < 512)
            stage_ab(gA, gB0, gB1, k0 + 64,
                     As + (cur ^ 1) * 4096, Bs + (cur ^ 1) * 8192, wave);
        const int ksw = (g ^ (mr & 3)) << 3;
        #pragma unroll
        for (int h = 0; h < 2; ++h) {
            bhalf8 a[2], b[4];
            #pragma unroll
            for (int i = 0; i < 2; ++i)
                a[i] = *(const bhalf8*)
                    &Ac[h * 2048 + (wm * 32 + i * 16 + mr) * 32 + ksw];
            #pragma unroll
            for (int j = 0; j < 4; ++j)
                b[j] = *(const bhalf8*)
                    &Bc[h * 4096 + (wn * 64 + j * 16 + mr) * 32 + ksw];
            #pragma unroll
            for (int i = 0; i < 2; ++i)
                #pragma unroll
                for (int j = 0; j < 4; ++j)
                    acc[i][j] = __builtin_amdgcn_mfma_f32_16x16x32_bf16(
                        a[i], b[j], acc[i][j], 0, 0, 0);
        }
    }

    #pragma unroll
    for (int i = 0; i < 2; ++i) {
        #pragma unroll
        for (int j = 0; j < 4; ++j) {
            const int gn = bn + wn * 64 + j * 16 + mr;
            const float bb = bias ? bias[gn] : 0.f;
            #pragma unroll
            for (int p = 0; p < 4; ++p) {
                const int gm = bm + wm * 32 + i * 16 + g * 4 + p;
                if (gm >= M) continue;
                Cbf[(size_t)gm * 512 + gn] = f2b(acc[i][j][p] + bb);
            }
        }
    }
}

// q-proj / kc-proj / Wc2 in one FLAT launch: 672 blocks.
// z=0 is Y-MAJOR (x=bid>>7): blocks sharing an A row-tile keep the same
// XCD across x-phases (y%8 invariant) -> A fetched ~once from HBM.
__global__ __launch_bounds__(256) void qkc_gemm(
    const ushort* __restrict__ encbf, const ushort* __restrict__ cebf,
    const ushort* __restrict__ wcbf,
    const ushort* __restrict__ wqbf, const ushort* __restrict__ wkbf,
    const ushort* __restrict__ wotbf,
    const float* __restrict__ bq, const float* __restrict__ bk,
    ushort* __restrict__ qbf, ushort* __restrict__ kcbf,
    ushort* __restrict__ wc2bf)
{
    __shared__ __align__(16) ushort As[2 * 64 * 64];
    __shared__ __align__(16) ushort Bs[2 * 128 * 64];
    const int bid = blockIdx.x;
    int z, x, y;
    if (bid < 512)      { z = 0; x = bid >> 7; y = bid & 127; }
    else if (bid < 640) { z = 1; x = (bid - 512) & 3; y = (bid - 512) >> 2; }
    else                { z = 2; x = (bid - 640) & 3; y = (bid - 640) >> 2; }
    const ushort* A = (z == 0) ? encbf : (z == 1) ? cebf : wcbf;
    const ushort* W = (z == 0) ? wqbf : (z == 1) ? wkbf : wotbf;
    const float* bias = (z == 0) ? bq : (z == 1) ? bk : nullptr;
    ushort* C = (z == 0) ? qbf : (z == 1) ? kcbf : wc2bf;
    const int M = (z == 0) ? 8192 : (z == 1) ? 2000 : 512;
    const int bm = y * 64;
    const int rowA = min(bm + (threadIdx.x >> 2), M - 1);
    gemm_body_512(A, W, bias, C, M, bm, x * 128, As, Bs, rowA);
}

// ---------------------------------------------------------------------------
// Stage-1 machinery. grid (16 m, 4 h, 8 nc), 2 tiles/block, dbuf Ks (64KB).
// ---------------------------------------------------------------------------
__device__ __forceinline__ void stage_ktile(
    ushort* Ks, const ushort* kcbf, int nt, int h, int w, int lane)
{
    #pragma unroll
    for (int it = 0; it < 8; ++it) {
        const int u = it * 256 + (w << 6) + lane;   // 0..2047
        const int nl = u >> 4, c = u & 15;
        gld16(Ks + (size_t)(it * 256 + (w << 6)) * 8,
              kcbf + (size_t)(nt * 128 + nl) * 512 + (h << 7)
                   + ((c ^ (nl & 7)) << 3));
    }
}

__device__ __forceinline__ void score_tile(
    const ushort* Ks, const bhalf8* aq, int mr, int g, f32x4* sacc)
{
    #pragma unroll
    for (int jn = 0; jn < 8; ++jn)
        #pragma unroll
        for (int p = 0; p < 4; ++p) sacc[jn][p] = 0.f;
    #pragma unroll
    for (int kd = 0; kd < 4; ++kd) {
        #pragma unroll
        for (int jn = 0; jn < 8; ++jn) {
            const int n = (jn << 4) + mr;
            const bhalf8 bk = *(const bhalf8*)
                &Ks[(n << 7) + ((((kd << 2) + g) ^ (n & 7)) << 3)];
            sacc[jn] = __builtin_amdgcn_mfma_f32_16x16x32_bf16(
                aq[kd], bk, sacc[jn], 0, 0, 0);
        }
    }
}

// A: rowsum partials. grid (16,4,8); rsp[(h*1024+row)*8 + nc].
__global__ __launch_bounds__(256) void rowsum_part(
    const ushort* __restrict__ qb, const ushort* __restrict__ kcbf,
    float* __restrict__ rsp)
{
    __shared__ __align__(16) ushort Ks[2 * 128 * 128];
    const int tid = threadIdx.x, w = tid >> 6, lane = tid & 63;
    const int mr = lane & 15, g = lane >> 4;
    const int h = blockIdx.y, nc = blockIdx.z;
    const int bm = blockIdx.x * 64;

    const ushort* qrow = qb + (size_t)(bm + (w << 4) + mr) * 512 + (h << 7);
    bhalf8 aq[4];
    #pragma unroll
    for (int kd = 0; kd < 4; ++kd)
        aq[kd] = *(const bhalf8*)(qrow + (g << 3) + (kd << 5));

    const int nt0 = nc * 2, nt1 = nc * 2 + 1;
    stage_ktile(Ks, kcbf, nt0, h, w, lane);
    __syncthreads();                                 // tile0 ready
    stage_ktile(Ks + 16384, kcbf, nt1, h, w, lane);  // tile1 in flight

    float rsl[4] = {0.f, 0.f, 0.f, 0.f};
    f32x4 sacc[8];
    score_tile(Ks, aq, mr, g, sacc);
    #pragma unroll
    for (int jn = 0; jn < 8; ++jn) {
        const bool valid = nt0 * 128 + (jn << 4) + mr < 2000;
        #pragma unroll
        for (int p = 0; p < 4; ++p)
            rsl[p] += valid ? __expf(sacc[jn][p] * SCALE) : 0.f;
    }
    __syncthreads();                                 // tile1 ready
    score_tile(Ks + 16384, aq, mr, g, sacc);
    #pragma unroll
    for (int jn = 0; jn < 8; ++jn) {
        const bool valid = nt1 * 128 + (jn << 4) + mr < 2000;
        #pragma unroll
        for (int p = 0; p < 4; ++p)
            rsl[p] += valid ? __expf(sacc[jn][p] * SCALE) : 0.f;
    }

    #pragma unroll
    for (int off = 1; off <= 8; off <<= 1)
        #pragma unroll
        for (int p = 0; p < 4; ++p)
            rsl[p] += __shfl_xor(rsl[p], off);
    if (mr == 0) {
        #pragma unroll
        for (int p = 0; p < 4; ++p) {
            const int row = (h << 10) + bm + (w << 4) + (g << 2) + p;
            rsp[(size_t)row * 8 + nc] = rsl[p];
        }
    }
}

// B: colsum partials. Same grid; part[slot][n], slot=((h*16+m)<<2)+w.
__global__ __launch_bounds__(256) void colsum_part(
    const ushort* __restrict__ qb, const ushort* __restrict__ kcbf,
    const float* __restrict__ rsp, float* __restrict__ part)
{
    __shared__ __align__(16) ushort Ks[2 * 128 * 128];
    const int tid = threadIdx.x, w = tid >> 6, lane = tid & 63;
    const int mr = lane & 15, g = lane >> 4;
    const int h = blockIdx.y, nc = blockIdx.z;
    const int bm = blockIdx.x * 64;
    const int slot = ((h * 16 + blockIdx.x) << 2) + w;

    const ushort* qrow = qb + (size_t)(bm + (w << 4) + mr) * 512 + (h << 7);
    bhalf8 aq[4];
    #pragma unroll
    for (int kd = 0; kd < 4; ++kd)
        aq[kd] = *(const bhalf8*)(qrow + (g << 3) + (kd << 5));

    float inv[4];
    #pragma unroll
    for (int p = 0; p < 4; ++p) {
        const int row = (h << 10) + bm + (w << 4) + (g << 2) + p;
        const float4 ra = *(const float4*)(rsp + (size_t)row * 8);
        const float4 rb = *(const float4*)(rsp + (size_t)row * 8 + 4);
        inv[p] = 1.f / (ra.x + ra.y + ra.z + ra.w + rb.x + rb.y + rb.z + rb.w);
    }

    const int nt0 = nc * 2, nt1 = nc * 2 + 1;
    stage_ktile(Ks, kcbf, nt0, h, w, lane);
    __syncthreads();
    stage_ktile(Ks + 16384, kcbf, nt1, h, w, lane);

    f32x4 sacc[8];
    #pragma unroll
    for (int t = 0; t < 2; ++t) {
        if (t == 1) __syncthreads();                 // tile1 ready
        const int nt = t ? nt1 : nt0;
        score_tile(t ? Ks + 16384 : Ks, aq, mr, g, sacc);
        #pragma unroll
        for (int jn = 0; jn < 8; ++jn) {
            const int n = nt * 128 + (jn << 4) + mr;
            const bool valid = n < 2000;
            float cv = 0.f;
            #pragma unroll
            for (int p = 0; p < 4; ++p)
                cv += valid ? __expf(sacc[jn][p] * SCALE) * inv[p] : 0.f;
            cv += __shfl_xor(cv, 16);
            cv += __shfl_xor(cv, 32);   // sum over the wave's 16 rows
            if (g == 0 && valid) part[(size_t)slot * 2000 + n] = cv;
        }
    }
}

// FULL reduction part[256][2000] -> cs[2000]; grid (8), 256 thr.
__global__ __launch_bounds__(256) void reduce_full_kernel(
    const float* __restrict__ part, float* __restrict__ cs)
{
    const int n = blockIdx.x * 256 + threadIdx.x;
    if (n >= 2000) return;
    float s = 0.f;
    for (int sl = 0; sl < 256; ++sl) s += part[(size_t)sl * 2000 + n];
    cs[n] = s;
}

// ---------------------------------------------------------------------------
// Top-101 of 2000 via MSB-first radix-select (ballot/popcount).
// ---------------------------------------------------------------------------
__global__ void topk_kernel(const float* __restrict__ cs,
                            int* __restrict__ idx)
{
    const int lane = threadIdx.x;   // block = 64
    const unsigned long long below = (1ull << lane) - 1ull;

    unsigned key[32];
    #pragma unroll
    for (int i = 0; i < 32; ++i) {
        const int n = lane + 64 * i;
        const float s = (n < 2000) ? cs[n] : -1e30f;
        const unsigned u = __float_as_uint(s);
        key[i] = u ^ ((unsigned)((int)u >> 31) | 0x80000000u);
    }

    unsigned prefix = 0;
    int remaining = 101;
    for (int b = 31; b >= 0; --b) {
        const unsigned tgt = (prefix << 1) | 1u;
        int cnt = 0;
        #pragma unroll
        for (int i = 0; i < 32; ++i)
            cnt += (int)__popcll(__ballot((key[i] >> b) == tgt));
        if (cnt >= remaining) prefix = tgt;
        else { remaining -= cnt; prefix = prefix << 1; }
    }
    const unsigned T = prefix;

    int base = 0;
    #pragma unroll
    for (int i = 0; i < 32; ++i) {
        const unsigned long long m = __ballot(key[i] > T);
        if (key[i] > T) idx[base + (int)__popcll(m & below)] = lane + 64 * i;
        base += (int)__popcll(m);
    }
    int r = remaining;
    #pragma unroll
    for (int i = 0; i < 32; ++i) {
        const unsigned long long m = __ballot(key[i] == T);
        const int cb = (int)__popcll(m & below);
        if (key[i] == T && cb < r) idx[base + cb] = lane + 64 * i;
        const int take = min(r, (int)__popcll(m));
        base += take; r -= take;
    }
}

// ---------------------------------------------------------------------------
// Fused k2/v2 projections with inline gather, dbuf BK=64 (z=0 k2; z=1 v2tp).
// ---------------------------------------------------------------------------
__global__ __launch_bounds__(256) void kv2_proj(
    const ushort* __restrict__ cebf, const int* __restrict__ idxbuf,
    const ushort* __restrict__ wkbf, const ushort* __restrict__ wvbf,
    const float* __restrict__ bk, const float* __restrict__ bv,
    ushort* __restrict__ k2bf, ushort* __restrict__ v2tp)
{
    __shared__ __align__(16) ushort As[2 * 64 * 64];
    __shared__ __align__(16) ushort Bs[2 * 128 * 64];
    const int z = blockIdx.z;
    const ushort* W = z ? wvbf : wkbf;
    const float* bias = z ? bv : bk;
    const int tid = threadIdx.x;
    const int wave = tid >> 6, lane = tid & 63;
    const int wm = wave >> 1, wn = wave & 1;
    const int mr = lane & 15, g = lane >> 4;
    const int bm = blockIdx.y * 64, bn = blockIdx.x * 128;

    f32x4 acc[2][4];
    #pragma unroll
    for (int i = 0; i < 2; ++i)
        #pragma unroll
        for (int j = 0; j < 4; ++j)
            #pragma unroll
            for (int p = 0; p < 4; ++p) acc[i][j][p] = 0.f;

    const int r0 = tid >> 2, c0 = tid & 3;
    const int cA = (c0 ^ (r0 & 3)) * 8;
    const int rA  = min(bm + r0, 100);
    const int srcrow = idxbuf[rA];               // inline gather
    const ushort* gA  = cebf + (size_t)srcrow * 512 + cA;
    const ushort* gB0 = W + (size_t)(bn + r0) * 512 + cA;
    const ushort* gB1 = W + (size_t)(bn + r0 + 64) * 512 + cA;

    stage_ab(gA, gB0, gB1, 0, As, Bs, wave);
    for (int k0 = 0; k0 < 512; k0 += 64) {
        const int cur = (k0 >> 6) & 1;
        ushort* Ac = As + cur * 4096;
        ushort* Bc = Bs + cur * 8192;
        __syncthreads();
        if (k0 + 64 < 512)
            stage_ab(gA, gB0, gB1, k0 + 64,
                     As + (cur ^ 1) * 4096, Bs + (cur ^ 1) * 8192, wave);
        const int ksw = (g ^ (mr & 3)) << 3;
        #pragma unroll
        for (int h = 0; h < 2; ++h) {
            bhalf8 a[2], b[4];
            #pragma unroll
            for (int i = 0; i < 2; ++i)
                a[i] = *(const bhalf8*)
                    &Ac[h * 2048 + (wm * 32 + i * 16 + mr) * 32 + ksw];
            #pragma unroll
            for (int j = 0; j < 4; ++j)
                b[j] = *(const bhalf8*)
                    &Bc[h * 4096 + (wn * 64 + j * 16 + mr) * 32 + ksw];
            #pragma unroll
            for (int i = 0; i < 2; ++i)
                #pragma unroll
                for (int j = 0; j < 4; ++j)
                    acc[i][j] = __builtin_amdgcn_mfma_f32_16x16x32_bf16(
                        a[i], b[j], acc[i][j], 0, 0, 0);
        }
    }

    #pragma unroll
    for (int i = 0; i < 2; ++i) {
        #pragma unroll
        for (int j = 0; j < 4; ++j) {
            const int gn = bn + wn * 64 + j * 16 + mr;
            const float bb = bias[gn];
            #pragma unroll
            for (int p = 0; p < 4; ++p) {
                const int gm = bm + wm * 32 + i * 16 + g * 4 + p;
                if (gm >= 101) continue;
                const ushort v = f2b(acc[i][j][p] + bb);
                if (z == 0) k2bf[(size_t)gm * 512 + gn] = v;
                else        v2tp[(size_t)gn * 128 + gm] = v;
            }
        }
    }
}

// ---------------------------------------------------------------------------
// Fused stage-2 attention, 8 waves x 128 rows per block. grid (64, 4).
// ---------------------------------------------------------------------------
__global__ __launch_bounds__(512) void attn2_fused(
    const ushort* __restrict__ qb, const ushort* __restrict__ k2bf,
    const ushort* __restrict__ v2tp, ushort* __restrict__ obf)
{
    __shared__ __align__(16) ushort K2s[128 * 128];
    __shared__ __align__(16) ushort V2s[128 * 128];
    __shared__ __align__(16) ushort Ps[8 * 16 * 128];
    const int tid = threadIdx.x, w = tid >> 6, lane = tid & 63;
    const int mr = lane & 15, g = lane >> 4;
    const int h = blockIdx.y;
    const int bm = blockIdx.x * 128;

    #pragma unroll
    for (int it = 0; it < 4; ++it) {
        const int cl = tid + 512 * it;      // 0..2047
        const int n = cl >> 4, c = cl & 15;
        uint4 kv = make_uint4(0u, 0u, 0u, 0u);
        if (n < 101)
            kv = *(const uint4*)(k2bf + (size_t)n * 512 + h * 128 + c * 8);
        *(uint4*)&K2s[(n << 7) + ((c ^ (n & 7)) << 3)] = kv;
        const uint4 vv = *(const uint4*)(v2tp + (((size_t)h << 7) + n) * 128 + c * 8);
        *(uint4*)&V2s[(n << 7) + ((c ^ (n & 7)) << 3)] = vv;
    }
    __syncthreads();

    f32x4 sacc[8];
    #pragma unroll
    for (int jn = 0; jn < 8; ++jn)
        #pragma unroll
        for (int p = 0; p < 4; ++p) sacc[jn][p] = 0.f;
    const ushort* qrow = qb + (size_t)(bm + (w << 4) + mr) * 512 + (h << 7);
    #pragma unroll
    for (int kd = 0; kd < 4; ++kd) {
        const bhalf8 aq = *(const bhalf8*)(qrow + (g << 3) + (kd << 5));
        #pragma unroll
        for (int jn = 0; jn < 8; ++jn) {
            const int n = (jn << 4) + mr;
            const bhalf8 bk = *(const bhalf8*)
                &K2s[(n << 7) + ((((kd << 2) + g) ^ (n & 7)) << 3)];
            sacc[jn] = __builtin_amdgcn_mfma_f32_16x16x32_bf16(aq, bk, sacc[jn], 0, 0, 0);
        }
    }

    float mrow[4] = {-1e30f, -1e30f, -1e30f, -1e30f};
    #pragma unroll
    for (int jn = 0; jn < 8; ++jn) {
        const bool valid = (jn < 6) || (jn == 6 && mr < 5);
        #pragma unroll
        for (int p = 0; p < 4; ++p) {
            const float s = valid ? sacc[jn][p] * SCALE : -1e30f;
            sacc[jn][p] = s;
            mrow[p] = fmaxf(mrow[p], s);
        }
    }
    #pragma unroll
    for (int off = 1; off <= 8; off <<= 1)
        #pragma unroll
        for (int p = 0; p < 4; ++p)
            mrow[p] = fmaxf(mrow[p], __shfl_xor(mrow[p], off));
    float srow[4] = {0.f, 0.f, 0.f, 0.f};
    #pragma unroll
    for (int jn = 0; jn < 8; ++jn)
        #pragma unroll
        for (int p = 0; p < 4; ++p) {
            const float e = __expf(sacc[jn][p] - mrow[p]);
            sacc[jn][p] = e;
            srow[p] += e;
        }
    #pragma unroll
    for (int off = 1; off <= 8; off <<= 1)
        #pragma unroll
        for (int p = 0; p < 4; ++p)
            srow[p] += __shfl_xor(srow[p], off);
    float inv[4];
    #pragma unroll
    for (int p = 0; p < 4; ++p) inv[p] = 1.f / srow[p];

    ushort* pw = Ps + (w << 11);
    #pragma unroll
    for (int jn = 0; jn < 8; ++jn) {
        const int cb = (jn << 1) + (mr >> 3);
        #pragma unroll
        for (int p = 0; p < 4; ++p) {
            const int r = (g << 2) + p;
            pw[(r << 7) + ((cb ^ (r & 7)) << 3) + (mr & 7)] =
                f2b(sacc[jn][p] * inv[p]);
        }
    }

    f32x4 oacc[8];
    #pragma unroll
    for (int jd = 0; jd < 8; ++jd)
        #pragma unroll
        for (int p = 0; p < 4; ++p) oacc[jd][p] = 0.f;
    #pragma unroll
    for (int kn = 0; kn < 4; ++kn) {
        const int ck = (kn << 2) + g;
        const bhalf8 ap = *(const bhalf8*)
            &pw[(mr << 7) + ((ck ^ (mr & 7)) << 3)];
        #pragma unroll
        for (int jd = 0; jd < 8; ++jd) {
            const int d = (jd << 4) + mr;
            const bhalf8 bv = *(const bhalf8*)
                &V2s[(d << 7) + ((ck ^ (d & 7)) << 3)];
            oacc[jd] = __builtin_amdgcn_mfma_f32_16x16x32_bf16(ap, bv, oacc[jd], 0, 0, 0);
        }
    }

    #pragma unroll
    for (int jd = 0; jd < 8; ++jd)
        #pragma unroll
        for (int p = 0; p < 4; ++p) {
            const int row = bm + (w << 4) + (g << 2) + p;
            obf[(size_t)row * 512 + (h << 7) + (jd << 4) + mr] = f2b(oacc[jd][p]);
        }
}

// ---------------------------------------------------------------------------
// Fused final projection + residual + LayerNorm, dbuf BK=64, 8 WAVES
// (512 thr): wave w -> row-half rh=w&1 (16 rows), col-quarter ch=w>>1
// (128 cols, 8 j-frags). LDS As 2x4KB + Bs 2x64KB + red 1KB ~= 137KB.
// ---------------------------------------------------------------------------
__device__ __forceinline__ void pl_stage(
    const ushort* gA, const ushort* gB, int k0,
    ushort* Asb, ushort* Bsb, int w)
{
    if (w < 2) {
        gld16(Asb + w * 512,        gA + k0);
        gld16(Asb + 1024 + w * 512, gA + k0 + 32);
    }
    #pragma unroll
    for (int r = 0; r < 4; ++r) {
        const int nb = r * 8 + w;              // 0..31 groups of 16 rows
        gld16(Bsb + nb * 512,         gB + nb * 8192 + k0);
        gld16(Bsb + 16384 + nb * 512, gB + nb * 8192 + k0 + 32);
    }
}

__global__ __launch_bounds__(512) void proj_ln(
    const ushort* __restrict__ obf, const ushort* __restrict__ wc2bf,
    const float* __restrict__ bc2, const float* __restrict__ enc,
    const float* __restrict__ gw, const float* __restrict__ bta,
    float* __restrict__ out)
{
    __shared__ __align__(16) ushort As[2 * 2048];
    __shared__ __align__(16) ushort Bs[2 * 32768];
    __shared__ float red1[4][32], red2[4][32];
    const int tid = threadIdx.x, w = tid >> 6, lane = tid & 63;
    const int mr = lane & 15, gq = lane >> 4;
    const int rh = w & 1, ch = w >> 1;          // ch in 0..3
    const int bm = blockIdx.x * 32;

    f32x4 acc[8];
    #pragma unroll
    for (int j = 0; j < 8; ++j)
        #pragma unroll
        for (int p = 0; p < 4; ++p) acc[j][p] = 0.f;

    const int lr = lane >> 2, lc = lane & 3;
    const int swc = (lc ^ (lr & 3)) * 8;
    const ushort* gA = obf + (size_t)(bm + ((w & 1) << 4) + lr) * 512 + swc;
    const ushort* gB = wc2bf + (size_t)lr * 512 + swc;

    pl_stage(gA, gB, 0, As, Bs, w);
    for (int k0 = 0; k0 < 512; k0 += 64) {
        const int cur = (k0 >> 6) & 1;
        ushort* Ac = As + cur * 2048;
        ushort* Bc = Bs + cur * 32768;
        __syncthreads();
        if (k0 + 64 < 512)
            pl_stage(gA, gB, k0 + 64,
                     As + (cur ^ 1) * 2048, Bs + (cur ^ 1) * 32768, w);
        const int ksw = (gq ^ (mr & 3)) << 3;
        #pragma unroll
        for (int h = 0; h < 2; ++h) {
            const bhalf8 a = *(const bhalf8*)
                &Ac[h * 1024 + (((rh << 4) + mr) << 5) + ksw];
            #pragma unroll
            for (int j = 0; j < 8; ++j) {
                const int n = (ch << 7) + (j << 4) + mr;
                const bhalf8 b = *(const bhalf8*)
                    &Bc[h * 16384 + (n << 5) + ksw];
                acc[j] = __builtin_amdgcn_mfma_f32_16x16x32_bf16(a, b, acc[j], 0, 0, 0);
            }
        }
    }

    float s1[4] = {0.f, 0.f, 0.f, 0.f}, s2[4] = {0.f, 0.f, 0.f, 0.f};
    #pragma unroll
    for (int j = 0; j < 8; ++j) {
        const int gcol = (ch << 7) + (j << 4) + mr;
        const float bb = bc2[gcol];
        #pragma unroll
        for (int p = 0; p < 4; ++p) {
            const int grow = bm + (rh << 4) + (gq << 2) + p;
            const float x = acc[j][p] + bb + enc[(size_t)grow * 512 + gcol];
            acc[j][p] = x;
            s1[p] += x;
            s2[p] += x * x;
        }
    }
    #pragma unroll
    for (int off = 1; off <= 8; off <<= 1)
        #pragma unroll
        for (int p = 0; p < 4; ++p) {
            s1[p] += __shfl_xor(s1[p], off);
            s2[p] += __shfl_xor(s2[p], off);
        }
    if (mr == 0) {
        #pragma unroll
        for (int p = 0; p < 4; ++p) {
            red1[ch][(rh << 4) + (gq << 2) + p] = s1[p];
            red2[ch][(rh << 4) + (gq << 2) + p] = s2[p];
        }
    }
    __syncthreads();
    float mu[4], rstd[4];
    #pragma unroll
    for (int p = 0; p < 4; ++p) {
        const int ri = (rh << 4) + (gq << 2) + p;
        const float t1 = red1[0][ri] + red1[1][ri] + red1[2][ri] + red1[3][ri];
        const float t2 = red2[0][ri] + red2[1][ri] + red2[2][ri] + red2[3][ri];
        const float m = t1 * (1.f / 512.f);
        mu[p] = m;
        rstd[p] = rsqrtf(t2 * (1.f / 512.f) - m * m + 1e-5f);
    }
    #pragma unroll
    for (int j = 0; j < 8; ++j) {
        const int gcol = (ch << 7) + (j << 4) + mr;
        const float gg = gw[gcol], bb = bta[gcol];
        #pragma unroll
        for (int p = 0; p < 4; ++p) {
            const int grow = bm + (rh << 4) + (gq << 2) + p;
            out[(size_t)grow * 512 + gcol] = (acc[j][p] - mu[p]) * rstd[p] * gg + bb;
        }
    }
}

extern "C" void kernel_launch(void* const* d_in, const int* in_sizes, int n_in,
                              void* d_out, int out_size, void* d_ws, size_t ws_size,
                              hipStream_t stream)
{
    const float* ce  = (const float*)d_in[0];
    const float* enc = (const float*)d_in[1];
    const float* wq  = (const float*)d_in[2];
    const float* bq  = (const float*)d_in[3];
    const float* wk  = (const float*)d_in[4];
    const float* bk  = (const float*)d_in[5];
    const float* wv  = (const float*)d_in[6];
    const float* bv  = (const float*)d_in[7];
    const float* wo  = (const float*)d_in[8];
    const float* bo  = (const float*)d_in[9];
    const float* wc  = (const float*)d_in[10];
    const float* bcb = (const float*)d_in[11];
    const float* lng = (const float*)d_in[12];
    const float* lnb = (const float*)d_in[13];
    float* ws  = (float*)d_ws;
    float* out = (float*)d_out;

    ushort* qbf    = (ushort*)(ws + OFF_QBF);
    ushort* encbf  = (ushort*)(ws + OFF_RB);     // -> kcbf -> obf
    ushort* kcbf   = (ushort*)(ws + OFF_RB);
    ushort* obf    = (ushort*)(ws + OFF_RB);
    float*  part   = ws + OFF_PART;
    float*  cs     = ws + OFF_CS;
    int*    idx    = (int*)(ws + OFF_IDX);
    float*  rsp    = ws + OFF_RSP;
    ushort* cebf   = (ushort*)(ws + OFF_CEBF);
    ushort* k2bf   = (ushort*)(ws + OFF_K2BF);
    ushort* v2tp   = (ushort*)(ws + OFF_V2TP);
    ushort* wqbf   = (ushort*)(ws + OFF_WQBF);
    ushort* wkbf   = (ushort*)(ws + OFF_WKBF);
    ushort* wvbf   = (ushort*)(ws + OFF_WVBF);
    ushort* wcbf   = (ushort*)(ws + OFF_WCBF);
    ushort* wotbf  = (ushort*)(ws + OFF_WOTBF);
    ushort* wc2bf  = (ushort*)(ws + OFF_WC2BF);
    float*  bc2    = ws + OFF_BC2;

    prep_kernel<<<6410, 256, 0, stream>>>(enc, ce, wq, wk, wv, wc, wo, bo, bcb,
                                          encbf, cebf, wqbf, wkbf, wvbf, wcbf,
                                          v2tp, wotbf, bc2);
    qkc_gemm<<<672, 256, 0, stream>>>(encbf, cebf, wcbf, wqbf, wkbf, wotbf,
                                      bq, bk, qbf, kcbf, wc2bf);
    rowsum_part<<<dim3(16, 4, 8), 256, 0, stream>>>(qbf, kcbf, rsp);
    colsum_part<<<dim3(16, 4, 8), 256, 0, stream>>>(qbf, kcbf, rsp, part);
    reduce_full_kernel<<<8, 256, 0, stream>>>(part, cs);
    topk_kernel<<<1, 64, 0, stream>>>(cs, idx);
    kv2_proj<<<dim3(4, 2, 2), 256, 0, stream>>>(cebf, idx, wkbf, wvbf, bk, bv,
                                                k2bf, v2tp);
    attn2_fused<<<dim3(64, 4), 512, 0, stream>>>(qbf, k2bf, v2tp, obf);
    proj_ln<<<256, 512, 0, stream>>>(obf, wc2bf, bc2, enc, lng, lnb, out);
    (void)in_sizes; (void)n_in; (void)out_size; (void)ws_size;
}

// Round 20
// 123.749 us; speedup vs baseline: 1.6993x; 1.0627x over previous
//
#include <hip/hip_runtime.h>
#include <hip/hip_bf16.h>

// ContextModule R20: colsum cross-wave LDS reduce -> part[64][2000] (4x less
// reduction traffic); topk radix from bit 30; attn2 Q loads hoisted above
// staging. 9 dispatches, ws 55.6 MB.

typedef short bhalf8 __attribute__((ext_vector_type(8)));   // 8 bf16 = 4 VGPR
typedef float f32x4 __attribute__((ext_vector_type(4)));

#define SCALE 0.08838834764831845f  // 1/sqrt(128)

// ---- ws layout (float offsets) ----
#define OFF_QBF    ((size_t)0)               // qbf bf16 [8192][512]
#define OFF_RB     ((size_t)6193152)         // encbf -> kcbf -> obf bf16 [8192][512]
#define OFF_TMP    ((size_t)8290304)
#define OFF_PART   (OFF_TMP)                 // [64][2000] f32 colsum partials
#define OFF_CS     (OFF_TMP + 1024000)       // cs [2048] f32
#define OFF_IDX    (OFF_TMP + 1026048)       // 128 ints
#define OFF_RSP    (OFF_TMP + 1026176)       // rowsum partials [4096][8] f32
#define OFF_CEBF   ((size_t)12484608)        // ce bf16 [2000][512]
#define OFF_K2BF   ((size_t)13022608)        // k2 bf16 [101][512]
#define OFF_V2TP   ((size_t)13074608)        // v2tp bf16 [4][128][128]
#define OFF_WQBF   ((size_t)13107376)
#define OFF_WKBF   ((size_t)13238448)
#define OFF_WVBF   ((size_t)13369520)
#define OFF_WCBF   ((size_t)13500592)
#define OFF_WOTBF  ((size_t)13631664)
#define OFF_WC2BF  ((size_t)13762736)
#define OFF_BC2    ((size_t)13893808)        // 512
// total 13,894,320 fl = 55.6 MB

__device__ __forceinline__ float bf2f(short u) {
    union { float f; unsigned int i; } x;
    x.i = ((unsigned int)(unsigned short)u) << 16;
    return x.f;
}
__device__ __forceinline__ ushort f2b(float f) {
    union { float f; unsigned int i; } x; x.f = f;
    return (ushort)((x.i + 0x7fff + ((x.i >> 16) & 1)) >> 16);  // RNE
}

// async global->LDS, 16B per lane; LDS dest = wave-uniform base + lane*16
__device__ __forceinline__ void gld16(ushort* lds, const ushort* g) {
    __builtin_amdgcn_global_load_lds(
        (const __attribute__((address_space(1))) unsigned int*)g,
        (__attribute__((address_space(3))) unsigned int*)lds, 16, 0, 0);
}

// ---------------------------------------------------------------------------
// prep: f32->bf16 conversions + v2tp zero + bc2 + wo-transpose, one launch.
// ---------------------------------------------------------------------------
__global__ __launch_bounds__(256) void prep_kernel(
    const float* __restrict__ enc, const float* __restrict__ ce,
    const float* __restrict__ wq, const float* __restrict__ wk,
    const float* __restrict__ wv, const float* __restrict__ wc,
    const float* __restrict__ wo, const float* __restrict__ bo,
    const float* __restrict__ bcb,
    ushort* __restrict__ encbf, ushort* __restrict__ cebf,
    ushort* __restrict__ wqbf, ushort* __restrict__ wkbf,
    ushort* __restrict__ wvbf, ushort* __restrict__ wcbf,
    ushort* __restrict__ v2tp, ushort* __restrict__ wotbf,
    float* __restrict__ bc2)
{
    __shared__ float tile[32][33];
    const int b = blockIdx.x, tid = threadIdx.x;
    const float* s; ushort* d; int n4, base;
    if (b < 4096)      { s = enc; d = encbf; n4 = 1048576; base = b; }
    else if (b < 5096) { s = ce;  d = cebf;  n4 = 256000;  base = b - 4096; }
    else if (b < 5352) { s = wq;  d = wqbf;  n4 = 65536;   base = b - 5096; }
    else if (b < 5608) { s = wk;  d = wkbf;  n4 = 65536;   base = b - 5352; }
    else if (b < 5864) { s = wv;  d = wvbf;  n4 = 65536;   base = b - 5608; }
    else if (b < 6120) { s = wc;  d = wcbf;  n4 = 65536;   base = b - 5864; }
    else if (b < 6152) {
        const int i = (b - 6120) * 256 + tid;          // 8192 uint4
        ((uint4*)v2tp)[i] = make_uint4(0u, 0u, 0u, 0u);
        return;
    } else if (b < 6154) {
        const int dd = (b - 6152) * 256 + tid;
        float acc = bcb[dd];
        const float4* wr = (const float4*)(wc + (size_t)dd * 512);
        const float4* br = (const float4*)bo;
        for (int m4 = 0; m4 < 128; ++m4) {
            const float4 w4 = wr[m4], b4 = br[m4];
            acc += w4.x * b4.x + w4.y * b4.y + w4.z * b4.z + w4.w * b4.w;
        }
        bc2[dd] = acc;
        return;
    } else {
        const int b2 = b - 6154;                       // 256 tiles
        const int bx = (b2 & 15) * 32, by = (b2 >> 4) * 32;
        const int tx = tid & 31, ty = tid >> 5;        // 32x8
        #pragma unroll
        for (int rr = 0; rr < 4; ++rr)
            tile[ty + 8 * rr][tx] = wo[(size_t)(by + ty + 8 * rr) * 512 + bx + tx];
        __syncthreads();
        #pragma unroll
        for (int rr = 0; rr < 4; ++rr)
            wotbf[(size_t)(bx + ty + 8 * rr) * 512 + by + tx] =
                f2b(tile[tx][ty + 8 * rr]);
        return;
    }
    const int i = base * 256 + tid;
    if (i >= n4) return;
    const float4 v = ((const float4*)s)[i];
    ushort4 r;
    r.x = f2b(v.x); r.y = f2b(v.y); r.z = f2b(v.z); r.w = f2b(v.w);
    ((ushort4*)d)[i] = r;
}

// ---------------------------------------------------------------------------
// 64x128 MFMA GEMM body, BK=64, double-buffered, one barrier per K-step.
// ---------------------------------------------------------------------------
__device__ __forceinline__ void stage_ab(
    const ushort* gA, const ushort* gB0, const ushort* gB1, int k0,
    ushort* As, ushort* Bs, int wave)
{
    gld16(As + wave * 512,        gA  + k0);
    gld16(As + 2048 + wave * 512, gA  + k0 + 32);
    gld16(Bs + wave * 512,        gB0 + k0);
    gld16(Bs + 4096 + wave * 512, gB0 + k0 + 32);
    gld16(Bs + 2048 + wave * 512, gB1 + k0);
    gld16(Bs + 6144 + wave * 512, gB1 + k0 + 32);
}

__device__ __forceinline__ void gemm_body_512(
    const ushort* A, const ushort* W, const float* bias, ushort* Cbf,
    int M, int bm, int bn, ushort* As, ushort* Bs, int rowA)
{
    const int tid = threadIdx.x;
    const int wave = tid >> 6, lane = tid & 63;
    const int wm = wave >> 1, wn = wave & 1;
    const int mr = lane & 15, g = lane >> 4;

    f32x4 acc[2][4];
    #pragma unroll
    for (int i = 0; i < 2; ++i)
        #pragma unroll
        for (int j = 0; j < 4; ++j)
            #pragma unroll
            for (int p = 0; p < 4; ++p) acc[i][j][p] = 0.f;

    const int r0 = tid >> 2, c0 = tid & 3;
    const int cA = (c0 ^ (r0 & 3)) * 8;
    const ushort* gA  = A + (size_t)rowA * 512 + cA;
    const ushort* gB0 = W + (size_t)(bn + r0) * 512 + cA;
    const ushort* gB1 = W + (size_t)(bn + r0 + 64) * 512 + cA;

    stage_ab(gA, gB0, gB1, 0, As, Bs, wave);
    for (int k0 = 0; k0 < 512; k0 += 64) {
        const int cur = (k0 >> 6) & 1;
        ushort* Ac = As + cur * 4096;
        ushort* Bc = Bs + cur * 8192;
        __syncthreads();   // drains cur's loads; other buf free
        if (k0 + 64 < 512)
            stage_ab(gA, gB0, gB1, k0 + 64,
                     As + (cur ^ 1) * 4096, Bs + (cur ^ 1) * 8192, wave);
        const int ksw = (g ^ (mr & 3)) << 3;
        #pragma unroll
        for (int h = 0; h < 2; ++h) {
            bhalf8 a[2], b[4];
            #pragma unroll
            for (int i = 0; i < 2; ++i)
                a[i] = *(const bhalf8*)
                    &Ac[h * 2048 + (wm * 32 + i * 16 + mr) * 32 + ksw];
            #pragma unroll
            for (int j = 0; j < 4; ++j)
                b[j] = *(const bhalf8*)
                    &Bc[h * 4096 + (wn * 64 + j * 16 + mr) * 32 + ksw];
            #pragma unroll
            for (int i = 0; i < 2; ++i)
                #pragma unroll
                for (int j = 0; j < 4; ++j)
                    acc[i][j] = __builtin_amdgcn_mfma_f32_16x16x32_bf16(
                        a[i], b[j], acc[i][j], 0, 0, 0);
        }
    }

    #pragma unroll
    for (int i = 0; i < 2; ++i) {
        #pragma unroll
        for (int j = 0; j < 4; ++j) {
            const int gn = bn + wn * 64 + j * 16 + mr;
            const float bb = bias ? bias[gn] : 0.f;
            #pragma unroll
            for (int p = 0; p < 4; ++p) {
                const int gm = bm + wm * 32 + i * 16 + g * 4 + p;
                if (gm >= M) continue;
                Cbf[(size_t)gm * 512 + gn] = f2b(acc[i][j][p] + bb);
            }
        }
    }
}

// q-proj / kc-proj / Wc2 in one FLAT launch: 672 blocks; z=0 y-major.
__global__ __launch_bounds__(256) void qkc_gemm(
    const ushort* __restrict__ encbf, const ushort* __restrict__ cebf,
    const ushort* __restrict__ wcbf,
    const ushort* __restrict__ wqbf, const ushort* __restrict__ wkbf,
    const ushort* __restrict__ wotbf,
    const float* __restrict__ bq, const float* __restrict__ bk,
    ushort* __restrict__ qbf, ushort* __restrict__ kcbf,
    ushort* __restrict__ wc2bf)
{
    __shared__ __align__(16) ushort As[2 * 64 * 64];
    __shared__ __align__(16) ushort Bs[2 * 128 * 64];
    const int bid = blockIdx.x;
    int z, x, y;
    if (bid < 512)      { z = 0; x = bid >> 7; y = bid & 127; }
    else if (bid < 640) { z = 1; x = (bid - 512) & 3; y = (bid - 512) >> 2; }
    else                { z = 2; x = (bid - 640) & 3; y = (bid - 640) >> 2; }
    const ushort* A = (z == 0) ? encbf : (z == 1) ? cebf : wcbf;
    const ushort* W = (z == 0) ? wqbf : (z == 1) ? wkbf : wotbf;
    const float* bias = (z == 0) ? bq : (z == 1) ? bk : nullptr;
    ushort* C = (z == 0) ? qbf : (z == 1) ? kcbf : wc2bf;
    const int M = (z == 0) ? 8192 : (z == 1) ? 2000 : 512;
    const int bm = y * 64;
    const int rowA = min(bm + (threadIdx.x >> 2), M - 1);
    gemm_body_512(A, W, bias, C, M, bm, x * 128, As, Bs, rowA);
}

// ---------------------------------------------------------------------------
// Stage-1 machinery. grid (16 m, 4 h, 8 nc), 2 tiles/block, dbuf Ks (64KB).
// ---------------------------------------------------------------------------
__device__ __forceinline__ void stage_ktile(
    ushort* Ks, const ushort* kcbf, int nt, int h, int w, int lane)
{
    #pragma unroll
    for (int it = 0; it < 8; ++it) {
        const int u = it * 256 + (w << 6) + lane;   // 0..2047
        const int nl = u >> 4, c = u & 15;
        gld16(Ks + (size_t)(it * 256 + (w << 6)) * 8,
              kcbf + (size_t)(nt * 128 + nl) * 512 + (h << 7)
                   + ((c ^ (nl & 7)) << 3));
    }
}

__device__ __forceinline__ void score_tile(
    const ushort* Ks, const bhalf8* aq, int mr, int g, f32x4* sacc)
{
    #pragma unroll
    for (int jn = 0; jn < 8; ++jn)
        #pragma unroll
        for (int p = 0; p < 4; ++p) sacc[jn][p] = 0.f;
    #pragma unroll
    for (int kd = 0; kd < 4; ++kd) {
        #pragma unroll
        for (int jn = 0; jn < 8; ++jn) {
            const int n = (jn << 4) + mr;
            const bhalf8 bk = *(const bhalf8*)
                &Ks[(n << 7) + ((((kd << 2) + g) ^ (n & 7)) << 3)];
            sacc[jn] = __builtin_amdgcn_mfma_f32_16x16x32_bf16(
                aq[kd], bk, sacc[jn], 0, 0, 0);
        }
    }
}

// A: rowsum partials. grid (16,4,8); rsp[(h*1024+row)*8 + nc].
__global__ __launch_bounds__(256) void rowsum_part(
    const ushort* __restrict__ qb, const ushort* __restrict__ kcbf,
    float* __restrict__ rsp)
{
    __shared__ __align__(16) ushort Ks[2 * 128 * 128];
    const int tid = threadIdx.x, w = tid >> 6, lane = tid & 63;
    const int mr = lane & 15, g = lane >> 4;
    const int h = blockIdx.y, nc = blockIdx.z;
    const int bm = blockIdx.x * 64;

    const ushort* qrow = qb + (size_t)(bm + (w << 4) + mr) * 512 + (h << 7);
    bhalf8 aq[4];
    #pragma unroll
    for (int kd = 0; kd < 4; ++kd)
        aq[kd] = *(const bhalf8*)(qrow + (g << 3) + (kd << 5));

    const int nt0 = nc * 2, nt1 = nc * 2 + 1;
    stage_ktile(Ks, kcbf, nt0, h, w, lane);
    __syncthreads();                                 // tile0 ready
    stage_ktile(Ks + 16384, kcbf, nt1, h, w, lane);  // tile1 in flight

    float rsl[4] = {0.f, 0.f, 0.f, 0.f};
    f32x4 sacc[8];
    score_tile(Ks, aq, mr, g, sacc);
    #pragma unroll
    for (int jn = 0; jn < 8; ++jn) {
        const bool valid = nt0 * 128 + (jn << 4) + mr < 2000;
        #pragma unroll
        for (int p = 0; p < 4; ++p)
            rsl[p] += valid ? __expf(sacc[jn][p] * SCALE) : 0.f;
    }
    __syncthreads();                                 // tile1 ready
    score_tile(Ks + 16384, aq, mr, g, sacc);
    #pragma unroll
    for (int jn = 0; jn < 8; ++jn) {
        const bool valid = nt1 * 128 + (jn << 4) + mr < 2000;
        #pragma unroll
        for (int p = 0; p < 4; ++p)
            rsl[p] += valid ? __expf(sacc[jn][p] * SCALE) : 0.f;
    }

    #pragma unroll
    for (int off = 1; off <= 8; off <<= 1)
        #pragma unroll
        for (int p = 0; p < 4; ++p)
            rsl[p] += __shfl_xor(rsl[p], off);
    if (mr == 0) {
        #pragma unroll
        for (int p = 0; p < 4; ++p) {
            const int row = (h << 10) + bm + (w << 4) + (g << 2) + p;
            rsp[(size_t)row * 8 + nc] = rsl[p];
        }
    }
}

// B: colsum partials. grid (16,4,8); cross-wave LDS reduce ->
// part[h*16+m][n] (64 slots), each block writes its 256-col slice.
__global__ __launch_bounds__(256) void colsum_part(
    const ushort* __restrict__ qb, const ushort* __restrict__ kcbf,
    const float* __restrict__ rsp, float* __restrict__ part)
{
    __shared__ __align__(16) ushort Ks[2 * 128 * 128];
    __shared__ float cred[4][128];
    const int tid = threadIdx.x, w = tid >> 6, lane = tid & 63;
    const int mr = lane & 15, g = lane >> 4;
    const int h = blockIdx.y, nc = blockIdx.z;
    const int bm = blockIdx.x * 64;
    const int slot = h * 16 + blockIdx.x;          // 0..63

    const ushort* qrow = qb + (size_t)(bm + (w << 4) + mr) * 512 + (h << 7);
    bhalf8 aq[4];
    #pragma unroll
    for (int kd = 0; kd < 4; ++kd)
        aq[kd] = *(const bhalf8*)(qrow + (g << 3) + (kd << 5));

    float inv[4];
    #pragma unroll
    for (int p = 0; p < 4; ++p) {
        const int row = (h << 10) + bm + (w << 4) + (g << 2) + p;
        const float4 ra = *(const float4*)(rsp + (size_t)row * 8);
        const float4 rb = *(const float4*)(rsp + (size_t)row * 8 + 4);
        inv[p] = 1.f / (ra.x + ra.y + ra.z + ra.w + rb.x + rb.y + rb.z + rb.w);
    }

    const int nt0 = nc * 2, nt1 = nc * 2 + 1;
    stage_ktile(Ks, kcbf, nt0, h, w, lane);
    __syncthreads();
    stage_ktile(Ks + 16384, kcbf, nt1, h, w, lane);

    f32x4 sacc[8];
    #pragma unroll
    for (int t = 0; t < 2; ++t) {
        if (t == 1) __syncthreads();                 // tile1 ready
        const int nt = t ? nt1 : nt0;
        score_tile(t ? Ks + 16384 : Ks, aq, mr, g, sacc);
        #pragma unroll
        for (int jn = 0; jn < 8; ++jn) {
            const int n = nt * 128 + (jn << 4) + mr;
            const bool valid = n < 2000;
            float cv = 0.f;
            #pragma unroll
            for (int p = 0; p < 4; ++p)
                cv += valid ? __expf(sacc[jn][p] * SCALE) * inv[p] : 0.f;
            cv += __shfl_xor(cv, 16);
            cv += __shfl_xor(cv, 32);   // sum over the wave's 16 rows
            if (g == 0) cred[w][(jn << 4) + mr] = cv;
        }
        __syncthreads();                             // cred complete
        if (tid < 128) {
            const int n = nt * 128 + tid;
            if (n < 2000)
                part[(size_t)slot * 2000 + n] =
                    cred[0][tid] + cred[1][tid] + cred[2][tid] + cred[3][tid];
        }
        __syncthreads();                             // cred reusable
    }
}

// FULL reduction part[64][2000] -> cs[2000]; grid (8), 256 thr.
__global__ __launch_bounds__(256) void reduce_full_kernel(
    const float* __restrict__ part, float* __restrict__ cs)
{
    const int n = blockIdx.x * 256 + threadIdx.x;
    if (n >= 2000) return;
    float s = 0.f;
    for (int sl = 0; sl < 64; ++sl) s += part[(size_t)sl * 2000 + n];
    cs[n] = s;
}

// ---------------------------------------------------------------------------
// Top-101 of 2000 via MSB-first radix-select (ballot/popcount).
// Valid keys all have bit31 set (positive floats) -> start at bit 30.
// ---------------------------------------------------------------------------
__global__ void topk_kernel(const float* __restrict__ cs,
                            int* __restrict__ idx)
{
    const int lane = threadIdx.x;   // block = 64
    const unsigned long long below = (1ull << lane) - 1ull;

    unsigned key[32];
    #pragma unroll
    for (int i = 0; i < 32; ++i) {
        const int n = lane + 64 * i;
        const float s = (n < 2000) ? cs[n] : -1e30f;
        const unsigned u = __float_as_uint(s);
        key[i] = u ^ ((unsigned)((int)u >> 31) | 0x80000000u);
    }

    unsigned prefix = 1u;           // bit31 == 1 for all valid keys
    int remaining = 101;
    for (int b = 30; b >= 0; --b) {
        const unsigned tgt = (prefix << 1) | 1u;
        int cnt = 0;
        #pragma unroll
        for (int i = 0; i < 32; ++i)
            cnt += (int)__popcll(__ballot((key[i] >> b) == tgt));
        if (cnt >= remaining) prefix = tgt;
        else { remaining -= cnt; prefix = prefix << 1; }
    }
    const unsigned T = prefix;

    int base = 0;
    #pragma unroll
    for (int i = 0; i < 32; ++i) {
        const unsigned long long m = __ballot(key[i] > T);
        if (key[i] > T) idx[base + (int)__popcll(m & below)] = lane + 64 * i;
        base += (int)__popcll(m);
    }
    int r = remaining;
    #pragma unroll
    for (int i = 0; i < 32; ++i) {
        const unsigned long long m = __ballot(key[i] == T);
        const int cb = (int)__popcll(m & below);
        if (key[i] == T && cb < r) idx[base + cb] = lane + 64 * i;
        const int take = min(r, (int)__popcll(m));
        base += take; r -= take;
    }
}

// ---------------------------------------------------------------------------
// Fused k2/v2 projections with inline gather, dbuf BK=64 (z=0 k2; z=1 v2tp).
// ---------------------------------------------------------------------------
__global__ __launch_bounds__(256) void kv2_proj(
    const ushort* __restrict__ cebf, const int* __restrict__ idxbuf,
    const ushort* __restrict__ wkbf, const ushort* __restrict__ wvbf,
    const float* __restrict__ bk, const float* __restrict__ bv,
    ushort* __restrict__ k2bf, ushort* __restrict__ v2tp)
{
    __shared__ __align__(16) ushort As[2 * 64 * 64];
    __shared__ __align__(16) ushort Bs[2 * 128 * 64];
    const int z = blockIdx.z;
    const ushort* W = z ? wvbf : wkbf;
    const float* bias = z ? bv : bk;
    const int tid = threadIdx.x;
    const int wave = tid >> 6, lane = tid & 63;
    const int wm = wave >> 1, wn = wave & 1;
    const int mr = lane & 15, g = lane >> 4;
    const int bm = blockIdx.y * 64, bn = blockIdx.x * 128;

    f32x4 acc[2][4];
    #pragma unroll
    for (int i = 0; i < 2; ++i)
        #pragma unroll
        for (int j = 0; j < 4; ++j)
            #pragma unroll
            for (int p = 0; p < 4; ++p) acc[i][j][p] = 0.f;

    const int r0 = tid >> 2, c0 = tid & 3;
    const int cA = (c0 ^ (r0 & 3)) * 8;
    const int rA  = min(bm + r0, 100);
    const int srcrow = idxbuf[rA];               // inline gather
    const ushort* gA  = cebf + (size_t)srcrow * 512 + cA;
    const ushort* gB0 = W + (size_t)(bn + r0) * 512 + cA;
    const ushort* gB1 = W + (size_t)(bn + r0 + 64) * 512 + cA;

    stage_ab(gA, gB0, gB1, 0, As, Bs, wave);
    for (int k0 = 0; k0 < 512; k0 += 64) {
        const int cur = (k0 >> 6) & 1;
        ushort* Ac = As + cur * 4096;
        ushort* Bc = Bs + cur * 8192;
        __syncthreads();
        if (k0 + 64 < 512)
            stage_ab(gA, gB0, gB1, k0 + 64,
                     As + (cur ^ 1) * 4096, Bs + (cur ^ 1) * 8192, wave);
        const int ksw = (g ^ (mr & 3)) << 3;
        #pragma unroll
        for (int h = 0; h < 2; ++h) {
            bhalf8 a[2], b[4];
            #pragma unroll
            for (int i = 0; i < 2; ++i)
                a[i] = *(const bhalf8*)
                    &Ac[h * 2048 + (wm * 32 + i * 16 + mr) * 32 + ksw];
            #pragma unroll
            for (int j = 0; j < 4; ++j)
                b[j] = *(const bhalf8*)
                    &Bc[h * 4096 + (wn * 64 + j * 16 + mr) * 32 + ksw];
            #pragma unroll
            for (int i = 0; i < 2; ++i)
                #pragma unroll
                for (int j = 0; j < 4; ++j)
                    acc[i][j] = __builtin_amdgcn_mfma_f32_16x16x32_bf16(
                        a[i], b[j], acc[i][j], 0, 0, 0);
        }
    }

    #pragma unroll
    for (int i = 0; i < 2; ++i) {
        #pragma unroll
        for (int j = 0; j < 4; ++j) {
            const int gn = bn + wn * 64 + j * 16 + mr;
            const float bb = bias[gn];
            #pragma unroll
            for (int p = 0; p < 4; ++p) {
                const int gm = bm + wm * 32 + i * 16 + g * 4 + p;
                if (gm >= 101) continue;
                const ushort v = f2b(acc[i][j][p] + bb);
                if (z == 0) k2bf[(size_t)gm * 512 + gn] = v;
                else        v2tp[(size_t)gn * 128 + gm] = v;
            }
        }
    }
}

// ---------------------------------------------------------------------------
// Fused stage-2 attention, 8 waves x 128 rows per block. grid (64, 4).
// Q fragments loaded BEFORE staging (latency overlaps LDS-DMA).
// ---------------------------------------------------------------------------
__global__ __launch_bounds__(512) void attn2_fused(
    const ushort* __restrict__ qb, const ushort* __restrict__ k2bf,
    const ushort* __restrict__ v2tp, ushort* __restrict__ obf)
{
    __shared__ __align__(16) ushort K2s[128 * 128];
    __shared__ __align__(16) ushort V2s[128 * 128];
    __shared__ __align__(16) ushort Ps[8 * 16 * 128];
    const int tid = threadIdx.x, w = tid >> 6, lane = tid & 63;
    const int mr = lane & 15, g = lane >> 4;
    const int h = blockIdx.y;
    const int bm = blockIdx.x * 128;

    // Q fragments first: global-load latency hides under K/V staging below
    const ushort* qrow = qb + (size_t)(bm + (w << 4) + mr) * 512 + (h << 7);
    bhalf8 aqr[4];
    #pragma unroll
    for (int kd = 0; kd < 4; ++kd)
        aqr[kd] = *(const bhalf8*)(qrow + (g << 3) + (kd << 5));

    #pragma unroll
    for (int it = 0; it < 4; ++it) {
        const int cl = tid + 512 * it;      // 0..2047
        const int n = cl >> 4, c = cl & 15;
        uint4 kv = make_uint4(0u, 0u, 0u, 0u);
        if (n < 101)
            kv = *(const uint4*)(k2bf + (size_t)n * 512 + h * 128 + c * 8);
        *(uint4*)&K2s[(n << 7) + ((c ^ (n & 7)) << 3)] = kv;
        const uint4 vv = *(const uint4*)(v2tp + (((size_t)h << 7) + n) * 128 + c * 8);
        *(uint4*)&V2s[(n << 7) + ((c ^ (n & 7)) << 3)] = vv;
    }
    __syncthreads();

    f32x4 sacc[8];
    #pragma unroll
    for (int jn = 0; jn < 8; ++jn)
        #pragma unroll
        for (int p = 0; p < 4; ++p) sacc[jn][p] = 0.f;
    #pragma unroll
    for (int kd = 0; kd < 4; ++kd) {
        #pragma unroll
        for (int jn = 0; jn < 8; ++jn) {
            const int n = (jn << 4) + mr;
            const bhalf8 bk = *(const bhalf8*)
                &K2s[(n << 7) + ((((kd << 2) + g) ^ (n & 7)) << 3)];
            sacc[jn] = __builtin_amdgcn_mfma_f32_16x16x32_bf16(aqr[kd], bk, sacc[jn], 0, 0, 0);
        }
    }

    float mrow[4] = {-1e30f, -1e30f, -1e30f, -1e30f};
    #pragma unroll
    for (int jn = 0; jn < 8; ++jn) {
        const bool valid = (jn < 6) || (jn == 6 && mr < 5);
        #pragma unroll
        for (int p = 0; p < 4; ++p) {
            const float s = valid ? sacc[jn][p] * SCALE : -1e30f;
            sacc[jn][p] = s;
            mrow[p] = fmaxf(mrow[p], s);
        }
    }
    #pragma unroll
    for (int off = 1; off <= 8; off <<= 1)
        #pragma unroll
        for (int p = 0; p < 4; ++p)
            mrow[p] = fmaxf(mrow[p], __shfl_xor(mrow[p], off));
    float srow[4] = {0.f, 0.f, 0.f, 0.f};
    #pragma unroll
    for (int jn = 0; jn < 8; ++jn)
        #pragma unroll
        for (int p = 0; p < 4; ++p) {
            const float e = __expf(sacc[jn][p] - mrow[p]);
            sacc[jn][p] = e;
            srow[p] += e;
        }
    #pragma unroll
    for (int off = 1; off <= 8; off <<= 1)
        #pragma unroll
        for (int p = 0; p < 4; ++p)
            srow[p] += __shfl_xor(srow[p], off);
    float inv[4];
    #pragma unroll
    for (int p = 0; p < 4; ++p) inv[p] = 1.f / srow[p];

    ushort* pw = Ps + (w << 11);
    #pragma unroll
    for (int jn = 0; jn < 8; ++jn) {
        const int cb = (jn << 1) + (mr >> 3);
        #pragma unroll
        for (int p = 0; p < 4; ++p) {
            const int r = (g << 2) + p;
            pw[(r << 7) + ((cb ^ (r & 7)) << 3) + (mr & 7)] =
                f2b(sacc[jn][p] * inv[p]);
        }
    }

    f32x4 oacc[8];
    #pragma unroll
    for (int jd = 0; jd < 8; ++jd)
        #pragma unroll
        for (int p = 0; p < 4; ++p) oacc[jd][p] = 0.f;
    #pragma unroll
    for (int kn = 0; kn < 4; ++kn) {
        const int ck = (kn << 2) + g;
        const bhalf8 ap = *(const bhalf8*)
            &pw[(mr << 7) + ((ck ^ (mr & 7)) << 3)];
        #pragma unroll
        for (int jd = 0; jd < 8; ++jd) {
            const int d = (jd << 4) + mr;
            const bhalf8 bv = *(const bhalf8*)
                &V2s[(d << 7) + ((ck ^ (d & 7)) << 3)];
            oacc[jd] = __builtin_amdgcn_mfma_f32_16x16x32_bf16(ap, bv, oacc[jd], 0, 0, 0);
        }
    }

    #pragma unroll
    for (int jd = 0; jd < 8; ++jd)
        #pragma unroll
        for (int p = 0; p < 4; ++p) {
            const int row = bm + (w << 4) + (g << 2) + p;
            obf[(size_t)row * 512 + (h << 7) + (jd << 4) + mr] = f2b(oacc[jd][p]);
        }
}

// ---------------------------------------------------------------------------
// Fused final projection + residual + LayerNorm, dbuf BK=64, 8 waves.
// ---------------------------------------------------------------------------
__device__ __forceinline__ void pl_stage(
    const ushort* gA, const ushort* gB, int k0,
    ushort* Asb, ushort* Bsb, int w)
{
    if (w < 2) {
        gld16(Asb + w * 512,        gA + k0);
        gld16(Asb + 1024 + w * 512, gA + k0 + 32);
    }
    #pragma unroll
    for (int r = 0; r < 4; ++r) {
        const int nb = r * 8 + w;              // 0..31 groups of 16 rows
        gld16(Bsb + nb * 512,         gB + nb * 8192 + k0);
        gld16(Bsb + 16384 + nb * 512, gB + nb * 8192 + k0 + 32);
    }
}

__global__ __launch_bounds__(512) void proj_ln(
    const ushort* __restrict__ obf, const ushort* __restrict__ wc2bf,
    const float* __restrict__ bc2, const float* __restrict__ enc,
    const float* __restrict__ gw, const float* __restrict__ bta,
    float* __restrict__ out)
{
    __shared__ __align__(16) ushort As[2 * 2048];
    __shared__ __align__(16) ushort Bs[2 * 32768];
    __shared__ float red1[4][32], red2[4][32];
    const int tid = threadIdx.x, w = tid >> 6, lane = tid & 63;
    const int mr = lane & 15, gq = lane >> 4;
    const int rh = w & 1, ch = w >> 1;          // ch in 0..3
    const int bm = blockIdx.x * 32;

    f32x4 acc[8];
    #pragma unroll
    for (int j = 0; j < 8; ++j)
        #pragma unroll
        for (int p = 0; p < 4; ++p) acc[j][p] = 0.f;

    const int lr = lane >> 2, lc = lane & 3;
    const int swc = (lc ^ (lr & 3)) * 8;
    const ushort* gA = obf + (size_t)(bm + ((w & 1) << 4) + lr) * 512 + swc;
    const ushort* gB = wc2bf + (size_t)lr * 512 + swc;

    pl_stage(gA, gB, 0, As, Bs, w);
    for (int k0 = 0; k0 < 512; k0 += 64) {
        const int cur = (k0 >> 6) & 1;
        ushort* Ac = As + cur * 2048;
        ushort* Bc = Bs + cur * 32768;
        __syncthreads();
        if (k0 + 64 < 512)
            pl_stage(gA, gB, k0 + 64,
                     As + (cur ^ 1) * 2048, Bs + (cur ^ 1) * 32768, w);
        const int ksw = (gq ^ (mr & 3)) << 3;
        #pragma unroll
        for (int h = 0; h < 2; ++h) {
            const bhalf8 a = *(const bhalf8*)
                &Ac[h * 1024 + (((rh << 4) + mr) << 5) + ksw];
            #pragma unroll
            for (int j = 0; j < 8; ++j) {
                const int n = (ch << 7) + (j << 4) + mr;
                const bhalf8 b = *(const bhalf8*)
                    &Bc[h * 16384 + (n << 5) + ksw];
                acc[j] = __builtin_amdgcn_mfma_f32_16x16x32_bf16(a, b, acc[j], 0, 0, 0);
            }
        }
    }

    float s1[4] = {0.f, 0.f, 0.f, 0.f}, s2[4] = {0.f, 0.f, 0.f, 0.f};
    #pragma unroll
    for (int j = 0; j < 8; ++j) {
        const int gcol = (ch << 7) + (j << 4) + mr;
        const float bb = bc2[gcol];
        #pragma unroll
        for (int p = 0; p < 4; ++p) {
            const int grow = bm + (rh << 4) + (gq << 2) + p;
            const float x = acc[j][p] + bb + enc[(size_t)grow * 512 + gcol];
            acc[j][p] = x;
            s1[p] += x;
            s2[p] += x * x;
        }
    }
    #pragma unroll
    for (int off = 1; off <= 8; off <<= 1)
        #pragma unroll
        for (int p = 0; p < 4; ++p) {
            s1[p] += __shfl_xor(s1[p], off);
            s2[p] += __shfl_xor(s2[p], off);
        }
    if (mr == 0) {
        #pragma unroll
        for (int p = 0; p < 4; ++p) {
            red1[ch][(rh << 4) + (gq << 2) + p] = s1[p];
            red2[ch][(rh << 4) + (gq << 2) + p] = s2[p];
        }
    }
    __syncthreads();
    float mu[4], rstd[4];
    #pragma unroll
    for (int p = 0; p < 4; ++p) {
        const int ri = (rh << 4) + (gq << 2) + p;
        const float t1 = red1[0][ri] + red1[1][ri] + red1[2][ri] + red1[3][ri];
        const float t2 = red2[0][ri] + red2[1][ri] + red2[2][ri] + red2[3][ri];
        const float m = t1 * (1.f / 512.f);
        mu[p] = m;
        rstd[p] = rsqrtf(t2 * (1.f / 512.f) - m * m + 1e-5f);
    }
    #pragma unroll
    for (int j = 0; j < 8; ++j) {
        const int gcol = (ch << 7) + (j << 4) + mr;
        const float gg = gw[gcol], bb = bta[gcol];
        #pragma unroll
        for (int p = 0; p < 4; ++p) {
            const int grow = bm + (rh << 4) + (gq << 2) + p;
            out[(size_t)grow * 512 + gcol] = (acc[j][p] - mu[p]) * rstd[p] * gg + bb;
        }
    }
}

extern "C" void kernel_launch(void* const* d_in, const int* in_sizes, int n_in,
                              void* d_out, int out_size, void* d_ws, size_t ws_size,
                              hipStream_t stream)
{
    const float* ce  = (const float*)d_in[0];
    const float* enc = (const float*)d_in[1];
    const float* wq  = (const float*)d_in[2];
    const float* bq  = (const float*)d_in[3];
    const float* wk  = (const float*)d_in[4];
    const float* bk  = (const float*)d_in[5];
    const float* wv  = (const float*)d_in[6];
    const float* bv  = (const float*)d_in[7];
    const float* wo  = (const float*)d_in[8];
    const float* bo  = (const float*)d_in[9];
    const float* wc  = (const float*)d_in[10];
    const float* bcb = (const float*)d_in[11];
    const float* lng = (const float*)d_in[12];
    const float* lnb = (const float*)d_in[13];
    float* ws  = (float*)d_ws;
    float* out = (float*)d_out;

    ushort* qbf    = (ushort*)(ws + OFF_QBF);
    ushort* encbf  = (ushort*)(ws + OFF_RB);     // -> kcbf -> obf
    ushort* kcbf   = (ushort*)(ws + OFF_RB);
    ushort* obf    = (ushort*)(ws + OFF_RB);
    float*  part   = ws + OFF_PART;
    float*  cs     = ws + OFF_CS;
    int*    idx    = (int*)(ws + OFF_IDX);
    float*  rsp    = ws + OFF_RSP;
    ushort* cebf   = (ushort*)(ws + OFF_CEBF);
    ushort* k2bf   = (ushort*)(ws + OFF_K2BF);
    ushort* v2tp   = (ushort*)(ws + OFF_V2TP);
    ushort* wqbf   = (ushort*)(ws + OFF_WQBF);
    ushort* wkbf   = (ushort*)(ws + OFF_WKBF);
    ushort* wvbf   = (ushort*)(ws + OFF_WVBF);
    ushort* wcbf   = (ushort*)(ws + OFF_WCBF);
    ushort* wotbf  = (ushort*)(ws + OFF_WOTBF);
    ushort* wc2bf  = (ushort*)(ws + OFF_WC2BF);
    float*  bc2    = ws + OFF_BC2;

    prep_kernel<<<6410, 256, 0, stream>>>(enc, ce, wq, wk, wv, wc, wo, bo, bcb,
                                          encbf, cebf, wqbf, wkbf, wvbf, wcbf,
                                          v2tp, wotbf, bc2);
    qkc_gemm<<<672, 256, 0, stream>>>(encbf, cebf, wcbf, wqbf, wkbf, wotbf,
                                      bq, bk, qbf, kcbf, wc2bf);
    rowsum_part<<<dim3(16, 4, 8), 256, 0, stream>>>(qbf, kcbf, rsp);
    colsum_part<<<dim3(16, 4, 8), 256, 0, stream>>>(qbf, kcbf, rsp, part);
    reduce_full_kernel<<<8, 256, 0, stream>>>(part, cs);
    topk_kernel<<<1, 64, 0, stream>>>(cs, idx);
    kv2_proj<<<dim3(4, 2, 2), 256, 0, stream>>>(cebf, idx, wkbf, wvbf, bk, bv,
                                                k2bf, v2tp);
    attn2_fused<<<dim3(64, 4), 512, 0, stream>>>(qbf, k2bf, v2tp, obf);
    proj_ln<<<256, 512, 0, stream>>>(obf, wc2bf, bc2, enc, lng, lnb, out);
    (void)in_sizes; (void)n_in; (void)out_size; (void)ws_size;
}